// Round 1
// baseline (2251.708 us; speedup 1.0000x reference)
//
#include <hip/hip_runtime.h>
#include <math.h>

#define L_ 128
#define D_ 128
#define H_ 8
#define V_ 32000
#define NROW 512
#define NEGC 1e9f

// ---------- one-time precompute ----------

// meansum[d] = sum_v E[v][d]
__global__ __launch_bounds__(256) void colsum_k(const float* __restrict__ E, float* __restrict__ meansum) {
    int t = threadIdx.x;
    int d = t & 127, h = t >> 7;
    int v0 = blockIdx.x * 256;
    float s = 0.f;
    for (int p = 0; p < 128; ++p)
        s += E[(v0 + h + 2 * p) * 128 + d];
    __shared__ float red[256];
    red[t] = s;
    __syncthreads();
    if (h == 0) atomicAdd(&meansum[d], red[d] + red[128 + d]);
}

// Tt[k][b][a*8+c] = T[k][a][b*8+c]   (transpose over (a,b), keep c)
__global__ __launch_bounds__(256) void transT_k(const float* __restrict__ T, float* __restrict__ Tt) {
    for (int q = 0; q < 4; ++q) {
        int id = blockIdx.x * 1024 + q * 256 + threadIdx.x;   // 0..262143
        int k = id >> 17;
        int rem = id & 131071;
        int a = rem >> 10;
        int bc = rem & 1023;
        int b = bc >> 3, c = bc & 7;
        Tt[k * 131072 + b * 1024 + a * 8 + c] = T[id];
    }
}

// ue = select(mm, colmean, x);  qz = softmax_D(ue*keep)*keep
__global__ __launch_bounds__(64) void init_k(const float* __restrict__ x, const int* __restrict__ mask,
                                             const int* __restrict__ m_mask, const float* __restrict__ meansum,
                                             float* __restrict__ ue, float* __restrict__ qz) {
    int row = blockIdx.x, t = threadIdx.x;
    float keepv = mask[row] ? 1.f : 0.f;
    bool mm = m_mask[row] != 0;
    float pre0 = meansum[t] * (1.f / 32000.f);
    float pre1 = meansum[t + 64] * (1.f / 32000.f);
    float u0 = mm ? pre0 : x[row * 128 + t];
    float u1 = mm ? pre1 : x[row * 128 + t + 64];
    ue[row * 128 + t] = u0;
    ue[row * 128 + t + 64] = u1;
    float sv0 = u0 * keepv, sv1 = u1 * keepv;
    float m = fmaxf(sv0, sv1);
    for (int off = 32; off; off >>= 1) m = fmaxf(m, __shfl_xor(m, off));
    float e0 = __expf(sv0 - m), e1 = __expf(sv1 - m);
    float s = e0 + e1;
    for (int off = 32; off; off >>= 1) s += __shfl_xor(s, off);
    float inv = keepv / s;
    qz[row * 128 + t] = e0 * inv;
    qz[row * 128 + t + 64] = e1 * inv;
}

// ---------- per-iteration kernels ----------

// per-row max & 1/sumexp over V of q_x
__global__ __launch_bounds__(256) void rowstat_k(const float* __restrict__ qx, float* __restrict__ rowm,
                                                 float* __restrict__ rowinv) {
    int row = blockIdx.x, t = threadIdx.x;
    const float* p = qx + (size_t)row * V_;
    float m = -3.4e38f, s = 0.f;
    for (int v = t; v < V_; v += 256) {
        float xv = p[v];
        if (xv <= m) s += __expf(xv - m);
        else { s = s * __expf(m - xv) + 1.f; m = xv; }
    }
    for (int off = 32; off; off >>= 1) {
        float m2 = __shfl_xor(m, off);
        float s2 = __shfl_xor(s, off);
        float M = fmaxf(m, m2);
        s = s * __expf(m - M) + s2 * __expf(m2 - M);
        m = M;
    }
    __shared__ float sm[4], ss[4];
    int w = t >> 6;
    if ((t & 63) == 0) { sm[w] = m; ss[w] = s; }
    __syncthreads();
    if (t == 0) {
        float M = sm[0], S = ss[0];
        for (int i = 1; i < 4; ++i) {
            float M2 = fmaxf(M, sm[i]);
            S = S * __expf(M - M2) + ss[i] * __expf(sm[i] - M2);
            M = M2;
        }
        rowm[row] = M;
        rowinv[row] = 1.f / S;
    }
}

// exbuf[row][d] += sum_k softmax(qx)[row][k] * E[k][d]   (split-K atomics)
__global__ __launch_bounds__(256) void exgemm_k(const float* __restrict__ qx, const float* __restrict__ E,
                                                const float* __restrict__ rowm, const float* __restrict__ rowinv,
                                                float* __restrict__ exbuf) {
    int t = threadIdx.x;
    int d = t & 127, rh = t >> 7;
    int rt0 = blockIdx.x * 64;
    int k0 = blockIdx.y * 1280;
    __shared__ float pL[64 * 32];
    float acc[32];
#pragma unroll
    for (int r = 0; r < 32; ++r) acc[r] = 0.f;
    for (int kt = 0; kt < 40; ++kt) {
        int kk0 = k0 + kt * 32;
        __syncthreads();
        for (int idx = t; idx < 2048; idx += 256) {
            int r = idx >> 5, kk = idx & 31;
            int row = rt0 + r;
            pL[idx] = __expf(qx[(size_t)row * V_ + kk0 + kk] - rowm[row]) * rowinv[row];
        }
        __syncthreads();
#pragma unroll
        for (int kq = 0; kq < 8; ++kq) {
            float e0 = E[(kk0 + kq * 4 + 0) * 128 + d];
            float e1 = E[(kk0 + kq * 4 + 1) * 128 + d];
            float e2 = E[(kk0 + kq * 4 + 2) * 128 + d];
            float e3 = E[(kk0 + kq * 4 + 3) * 128 + d];
#pragma unroll
            for (int r = 0; r < 32; ++r) {
                const float4 pv = *(const float4*)&pL[(rh * 32 + r) * 32 + kq * 4];
                acc[r] += pv.x * e0 + pv.y * e1 + pv.z * e2 + pv.w * e3;
            }
        }
    }
#pragma unroll
    for (int r = 0; r < 32; ++r)
        atomicAdd(&exbuf[(rt0 + rh * 32 + r) * 128 + d], acc[r]);
}

__global__ __launch_bounds__(128) void uecomb_k(const float* __restrict__ x, const int* __restrict__ m_mask,
                                                const float* __restrict__ exbuf, float* __restrict__ ue) {
    int row = blockIdx.x, t = threadIdx.x;
    bool mm = m_mask[row] != 0;
    ue[row * 128 + t] = mm ? exbuf[row * 128 + t] : x[row * 128 + t];
}

// U2[(z*2+k)][i][(b*8+c)] = sum_a qz[z,i,a] T[k][a][(b,c)]
// W2[(z*2+k)][j][(a*8+c)] = sum_b qz[z,j,b] Tt[k][b][(a,c)]
__global__ __launch_bounds__(256) void uwgemm_k(const float* __restrict__ qz, const float* __restrict__ T,
                                                const float* __restrict__ Tt, float* __restrict__ U2,
                                                float* __restrict__ W2) {
    int t = threadIdx.x;
    int by = blockIdx.y;            // 16: uw(2) x z(4) x k(2)
    int uw = by >> 3, z = (by >> 1) & 3, k = by & 1;
    int bx = blockIdx.x;            // 32: mt(8) x nt(4)
    int m0 = (bx >> 2) * 16, n = (bx & 3) * 256 + t;
    const float* A = qz + z * 16384;
    const float* Bm = (uw ? Tt : T) + k * 131072;
    float* Cm = (uw ? W2 : U2) + (z * 2 + k) * 131072;
    __shared__ float aL[2048];
    for (int idx = t; idx < 2048; idx += 256)
        aL[idx] = A[(m0 + (idx >> 7)) * 128 + (idx & 127)];
    __syncthreads();
    float acc[16];
#pragma unroll
    for (int m = 0; m < 16; ++m) acc[m] = 0.f;
    for (int kq = 0; kq < 32; ++kq) {
        float b0 = Bm[(kq * 4 + 0) * 1024 + n];
        float b1 = Bm[(kq * 4 + 1) * 1024 + n];
        float b2 = Bm[(kq * 4 + 2) * 1024 + n];
        float b3 = Bm[(kq * 4 + 3) * 1024 + n];
#pragma unroll
        for (int m = 0; m < 16; ++m) {
            const float4 aq = *(const float4*)&aL[m * 128 + kq * 4];
            acc[m] += aq.x * b0 + aq.y * b1 + aq.z * b2 + aq.w * b3;
        }
    }
#pragma unroll
    for (int m = 0; m < 16; ++m)
        Cm[(m0 + m) * 1024 + n] = acc[m];
}

// q_hn[z,c,i,:] = softmax_j( F ) with diag/invalid = -NEG;  also writes transposed copy
__global__ __launch_bounds__(256) void qhn_k(const float* __restrict__ qz, const float* __restrict__ U2,
                                             const int* __restrict__ mask, float* __restrict__ qhn,
                                             float* __restrict__ qhnT) {
    int bid = blockIdx.x;
    int z = bid >> 7, i = bid & 127;
    int t = threadIdx.x;
    __shared__ float uL[2048];
    __shared__ float qzC[128 * 33];
    __shared__ float fL[1024];
    {
        const float* ub = U2 + z * 262144 + i * 1024;
        for (int idx = t; idx < 2048; idx += 256) {
            int k = idx >> 10, bc = idx & 1023;
            uL[idx] = ub[k * 131072 + bc];
        }
    }
    int j = t & 127, ch = t >> 7;
    int kSel = (j > i) ? 0 : 1;
    const int ubase = kSel * 1024 + ch;
    float acc4[4] = {0.f, 0.f, 0.f, 0.f};
    for (int bcn = 0; bcn < 4; ++bcn) {
        __syncthreads();
        for (int idx = t; idx < 4096; idx += 256) {
            int jj = idx >> 5, bb = idx & 31;
            qzC[jj * 33 + bb] = qz[z * 16384 + jj * 128 + bcn * 32 + bb];
        }
        __syncthreads();
#pragma unroll 8
        for (int bb = 0; bb < 32; ++bb) {
            float qv = qzC[j * 33 + bb];
            int b8 = (bcn * 32 + bb) * 8;
            acc4[0] += uL[ubase + b8] * qv;
            acc4[1] += uL[ubase + b8 + 2] * qv;
            acc4[2] += uL[ubase + b8 + 4] * qv;
            acc4[3] += uL[ubase + b8 + 6] * qv;
        }
    }
    bool vi = mask[z * 128 + i] != 0;
    bool vj = mask[z * 128 + j] != 0;
#pragma unroll
    for (int g = 0; g < 4; ++g) {
        float F = acc4[g];
        if (j == i) F -= NEGC;
        if (!vi || !vj) F = -NEGC;
        fL[(2 * g + ch) * 128 + j] = F;
    }
    __syncthreads();
    int c = t >> 5, lane = t & 31;
    float mval = -3.4e38f;
#pragma unroll
    for (int q = 0; q < 4; ++q) mval = fmaxf(mval, fL[c * 128 + lane + q * 32]);
    for (int off = 16; off; off >>= 1) mval = fmaxf(mval, __shfl_xor(mval, off, 32));
    float ssum = 0.f;
#pragma unroll
    for (int q = 0; q < 4; ++q) ssum += __expf(fL[c * 128 + lane + q * 32] - mval);
    for (int off = 16; off; off >>= 1) ssum += __shfl_xor(ssum, off, 32);
    float inv = 1.f / ssum;
#pragma unroll
    for (int q = 0; q < 4; ++q) {
        int j2 = lane + q * 32;
        float val = __expf(fL[c * 128 + j2] - mval) * inv;
        qhn[((z * 8 + c) * 128 + i) * 128 + j2] = val;
        qhnT[((z * 8 + c) * 128 + j2) * 128 + i] = val;
    }
}

// mode 0: G1[z,i,a] = sum_{c,s} hn[c,i,s] * W2[k(s,i)][s][(a,c)]   (k=0 iff s>i)
// mode 1: G2[z,j,b] = sum_{c,s} hn[c,s,j] * U2[k(s,j)][s][(b,c)]   (k=0 iff s<j)
__global__ __launch_bounds__(256) void gkern_k(const float* __restrict__ qhn, const float* __restrict__ qhnT,
                                               const float* __restrict__ U2, const float* __restrict__ W2,
                                               float* __restrict__ g1, float* __restrict__ g2) {
    int mode = blockIdx.y;
    int z = blockIdx.x >> 5;
    int t0 = (blockIdx.x & 31) * 4;
    int t = threadIdx.x;
    __shared__ float hnL[4 * 8 * 128];   // [ii][c][s]
    __shared__ float red[2 * 4 * 128];
    const float* hsrc = mode ? qhnT : qhn;
    for (int idx = t; idx < 4096; idx += 256) {
        int ii = idx >> 10, rem = idx & 1023;
        int c = rem >> 7, s = rem & 127;
        hnL[idx] = hsrc[((z * 8 + c) * 128 + t0 + ii) * 128 + s];
    }
    __syncthreads();
    int a = t & 127, ch = t >> 7, cb = ch * 4;
    const float* M0 = (mode ? U2 : W2) + z * 262144;
    const float* M1 = M0 + 131072;
    float acc[4] = {0.f, 0.f, 0.f, 0.f};
    const float4 zero4 = {0.f, 0.f, 0.f, 0.f};
    for (int s = 0; s < 128; ++s) {
        bool n0 = mode ? (s < t0 + 3) : (s > t0);
        bool n1 = mode ? (s > t0) : (s < t0 + 3);
        float4 w0 = n0 ? *(const float4*)&M0[s * 1024 + a * 8 + cb] : zero4;
        float4 w1 = n1 ? *(const float4*)&M1[s * 1024 + a * 8 + cb] : zero4;
#pragma unroll
        for (int ii = 0; ii < 4; ++ii) {
            int o = t0 + ii;
            bool u0 = mode ? (s < o) : (s > o);
            float4 wv = u0 ? w0 : w1;
            const float* hrow = &hnL[(ii * 8 + cb) * 128 + s];
            acc[ii] += hrow[0] * wv.x + hrow[128] * wv.y + hrow[256] * wv.z + hrow[384] * wv.w;
        }
    }
#pragma unroll
    for (int ii = 0; ii < 4; ++ii) red[(ch * 4 + ii) * 128 + a] = acc[ii];
    __syncthreads();
    if (ch == 0) {
        float* Gout = mode ? g2 : g1;
#pragma unroll
        for (int ii = 0; ii < 4; ++ii) {
            float v = red[ii * 128 + t] + red[(4 + ii) * 128 + t];
            Gout[(z * 128 + t0 + ii) * 128 + t] = v;
        }
    }
}

// qz = softmax_D(ue + g1 + g2) * keep
__global__ __launch_bounds__(64) void zupd_k(const float* __restrict__ ue, const float* __restrict__ g1,
                                             const float* __restrict__ g2, const int* __restrict__ mask,
                                             float* __restrict__ qz) {
    int row = blockIdx.x, t = threadIdx.x;
    float keepv = mask[row] ? 1.f : 0.f;
    int b = row * 128;
    float v0 = ue[b + t] + g1[b + t] + g2[b + t];
    float v1 = ue[b + t + 64] + g1[b + t + 64] + g2[b + t + 64];
    float m = fmaxf(v0, v1);
    for (int off = 32; off; off >>= 1) m = fmaxf(m, __shfl_xor(m, off));
    float e0 = __expf(v0 - m), e1 = __expf(v1 - m);
    float s = e0 + e1;
    for (int off = 32; off; off >>= 1) s += __shfl_xor(s, off);
    float inv = keepv / s;
    qz[b + t] = e0 * inv;
    qz[b + t + 64] = e1 * inv;
}

// out[row][v] = sum_a qz[row][a] * E[v][a]
__global__ __launch_bounds__(256) void msgx_k(const float* __restrict__ qz, const float* __restrict__ E,
                                              float* __restrict__ out) {
    int t = threadIdx.x;
    int rt0 = blockIdx.x * 64;
    int vbase = blockIdx.y * 256;
    __shared__ float qzL[64 * 128];
    __shared__ float eL[128 * 33];
    for (int idx = t; idx < 8192; idx += 256)
        qzL[idx] = qz[rt0 * 128 + idx];
    int v_l = t & 31, rg = t >> 5;
    int r0 = rg * 8;
    for (int stage = 0; stage < 8; ++stage) {
        int vb = vbase + stage * 32;
        __syncthreads();
        for (int idx = t; idx < 4096; idx += 256) {
            int vv = idx >> 7, aa = idx & 127;
            eL[aa * 33 + vv] = E[(vb + vv) * 128 + aa];
        }
        __syncthreads();
        float acc[8] = {0, 0, 0, 0, 0, 0, 0, 0};
        for (int a4 = 0; a4 < 32; ++a4) {
            float e0 = eL[(a4 * 4 + 0) * 33 + v_l];
            float e1 = eL[(a4 * 4 + 1) * 33 + v_l];
            float e2 = eL[(a4 * 4 + 2) * 33 + v_l];
            float e3 = eL[(a4 * 4 + 3) * 33 + v_l];
#pragma unroll
            for (int rr = 0; rr < 8; ++rr) {
                const float4 q = *(const float4*)&qzL[(r0 + rr) * 128 + a4 * 4];
                acc[rr] += q.x * e0 + q.y * e1 + q.z * e2 + q.w * e3;
            }
        }
#pragma unroll
        for (int rr = 0; rr < 8; ++rr)
            out[(size_t)(rt0 + r0 + rr) * V_ + vb + v_l] = acc[rr];
    }
}

extern "C" void kernel_launch(void* const* d_in, const int* in_sizes, int n_in,
                              void* d_out, int out_size, void* d_ws, size_t ws_size,
                              hipStream_t stream) {
    const float* x     = (const float*)d_in[0];   // [B,L,D]
    const int*   mask  = (const int*)d_in[1];     // [B,L]
    const float* E     = (const float*)d_in[2];   // [V,D]
    const int*   mmask = (const int*)d_in[3];     // [B,L]
    const float* T     = (const float*)d_in[4];   // [2,D,D,H]
    float* out = (float*)d_out;                   // [B,L,V]

    float* w = (float*)d_ws;
    float* meansum = w;                 // 128
    float* ue      = w + 128;           // 65536
    float* qz      = ue + 65536;        // 65536
    float* exbuf   = qz + 65536;        // 65536
    float* g1      = exbuf + 65536;     // 65536
    float* g2      = g1 + 65536;        // 65536
    float* rowm    = g2 + 65536;        // 512
    float* rowinv  = rowm + 512;        // 512
    float* Tt      = rowinv + 512;      // 262144
    float* U2      = Tt + 262144;       // 1048576
    float* W2      = U2 + 1048576;      // 1048576
    float* qhn     = W2 + 1048576;      // 524288
    float* qhnT    = qhn + 524288;      // 524288  -> total ~14.3 MB

    hipMemsetAsync(meansum, 0, 128 * sizeof(float), stream);
    colsum_k<<<125, 256, 0, stream>>>(E, meansum);
    transT_k<<<256, 256, 0, stream>>>(T, Tt);
    init_k<<<512, 64, 0, stream>>>(x, mask, mmask, meansum, ue, qz);

    for (int it = 0; it < 4; ++it) {
        if (it) {
            rowstat_k<<<512, 256, 0, stream>>>(out, rowm, rowinv);
            hipMemsetAsync(exbuf, 0, 65536 * sizeof(float), stream);
            exgemm_k<<<dim3(8, 25), 256, 0, stream>>>(out, E, rowm, rowinv, exbuf);
            uecomb_k<<<512, 128, 0, stream>>>(x, mmask, exbuf, ue);
        }
        uwgemm_k<<<dim3(32, 16), 256, 0, stream>>>(qz, T, Tt, U2, W2);
        qhn_k<<<512, 256, 0, stream>>>(qz, U2, mask, qhn, qhnT);
        gkern_k<<<dim3(128, 2), 256, 0, stream>>>(qhn, qhnT, U2, W2, g1, g2);
        zupd_k<<<512, 64, 0, stream>>>(ue, g1, g2, mask, qz);
        msgx_k<<<dim3(8, 125), 256, 0, stream>>>(qz, E, out);
    }
}

// Round 2
// 1645.632 us; speedup vs baseline: 1.3683x; 1.3683x over previous
//
#include <hip/hip_runtime.h>
#include <math.h>

#define L_ 128
#define D_ 128
#define H_ 8
#define V_ 32000
#define NROW 512
#define NEGC 1e9f

// ---------- one-time precompute ----------

// meansum[d] = sum_v E[v][d]
__global__ __launch_bounds__(256) void colsum_k(const float* __restrict__ E, float* __restrict__ meansum) {
    int t = threadIdx.x;
    int d = t & 127, h = t >> 7;
    int v0 = blockIdx.x * 256;
    float s = 0.f;
    for (int p = 0; p < 128; ++p)
        s += E[(v0 + h + 2 * p) * 128 + d];
    __shared__ float red[256];
    red[t] = s;
    __syncthreads();
    if (h == 0) atomicAdd(&meansum[d], red[d] + red[128 + d]);
}

// Tt[k][b][a*8+c] = T[k][a][b*8+c]   (transpose over (a,b), keep c)
__global__ __launch_bounds__(256) void transT_k(const float* __restrict__ T, float* __restrict__ Tt) {
    for (int q = 0; q < 4; ++q) {
        int id = blockIdx.x * 1024 + q * 256 + threadIdx.x;   // 0..262143
        int k = id >> 17;
        int rem = id & 131071;
        int a = rem >> 10;
        int bc = rem & 1023;
        int b = bc >> 3, c = bc & 7;
        Tt[k * 131072 + b * 1024 + a * 8 + c] = T[id];
    }
}

// ue = select(mm, colmean, x);  qz = softmax_D(ue*keep)*keep
__global__ __launch_bounds__(64) void init_k(const float* __restrict__ x, const int* __restrict__ mask,
                                             const int* __restrict__ m_mask, const float* __restrict__ meansum,
                                             float* __restrict__ ue, float* __restrict__ qz) {
    int row = blockIdx.x, t = threadIdx.x;
    float keepv = mask[row] ? 1.f : 0.f;
    bool mm = m_mask[row] != 0;
    float pre0 = meansum[t] * (1.f / 32000.f);
    float pre1 = meansum[t + 64] * (1.f / 32000.f);
    float u0 = mm ? pre0 : x[row * 128 + t];
    float u1 = mm ? pre1 : x[row * 128 + t + 64];
    ue[row * 128 + t] = u0;
    ue[row * 128 + t + 64] = u1;
    float sv0 = u0 * keepv, sv1 = u1 * keepv;
    float m = fmaxf(sv0, sv1);
    for (int off = 32; off; off >>= 1) m = fmaxf(m, __shfl_xor(m, off));
    float e0 = __expf(sv0 - m), e1 = __expf(sv1 - m);
    float s = e0 + e1;
    for (int off = 32; off; off >>= 1) s += __shfl_xor(s, off);
    float inv = keepv / s;
    qz[row * 128 + t] = e0 * inv;
    qz[row * 128 + t + 64] = e1 * inv;
}

// ---------- per-iteration kernels ----------

// per-row max & 1/sumexp over V of q_x
__global__ __launch_bounds__(256) void rowstat_k(const float* __restrict__ qx, float* __restrict__ rowm,
                                                 float* __restrict__ rowinv) {
    int row = blockIdx.x, t = threadIdx.x;
    const float* p = qx + (size_t)row * V_;
    float m = -3.4e38f, s = 0.f;
    for (int v = t; v < V_; v += 256) {
        float xv = p[v];
        if (xv <= m) s += __expf(xv - m);
        else { s = s * __expf(m - xv) + 1.f; m = xv; }
    }
    for (int off = 32; off; off >>= 1) {
        float m2 = __shfl_xor(m, off);
        float s2 = __shfl_xor(s, off);
        float M = fmaxf(m, m2);
        s = s * __expf(m - M) + s2 * __expf(m2 - M);
        m = M;
    }
    __shared__ float sm[4], ss[4];
    int w = t >> 6;
    if ((t & 63) == 0) { sm[w] = m; ss[w] = s; }
    __syncthreads();
    if (t == 0) {
        float M = sm[0], S = ss[0];
        for (int i = 1; i < 4; ++i) {
            float M2 = fmaxf(M, sm[i]);
            S = S * __expf(M - M2) + ss[i] * __expf(sm[i] - M2);
            M = M2;
        }
        rowm[row] = M;
        rowinv[row] = 1.f / S;
    }
}

// exbuf[row][d] += sum_k softmax(qx)[row][k] * E[k][d]   (split-K atomics)
// Re-tiled for occupancy: 32 rows x 320 K per block -> grid 16x100 = 1600 blocks
// (was 8x25 = 200 blocks -> <1 block/CU, latency-bound at 24% VALUBusy)
__global__ __launch_bounds__(256) void exgemm_k(const float* __restrict__ qx, const float* __restrict__ E,
                                                const float* __restrict__ rowm, const float* __restrict__ rowinv,
                                                float* __restrict__ exbuf) {
    int t = threadIdx.x;
    int d = t & 127, rh = t >> 7;
    int rt0 = blockIdx.x * 32;
    int k0 = blockIdx.y * 320;
    __shared__ float pL[32 * 32];
    float acc[16];
#pragma unroll
    for (int r = 0; r < 16; ++r) acc[r] = 0.f;
    for (int kt = 0; kt < 10; ++kt) {
        int kk0 = k0 + kt * 32;
        __syncthreads();
        for (int idx = t; idx < 1024; idx += 256) {
            int r = idx >> 5, kk = idx & 31;
            int row = rt0 + r;
            pL[idx] = __expf(qx[(size_t)row * V_ + kk0 + kk] - rowm[row]) * rowinv[row];
        }
        __syncthreads();
#pragma unroll
        for (int kq = 0; kq < 8; ++kq) {
            float e0 = E[(kk0 + kq * 4 + 0) * 128 + d];
            float e1 = E[(kk0 + kq * 4 + 1) * 128 + d];
            float e2 = E[(kk0 + kq * 4 + 2) * 128 + d];
            float e3 = E[(kk0 + kq * 4 + 3) * 128 + d];
#pragma unroll
            for (int r = 0; r < 16; ++r) {
                const float4 pv = *(const float4*)&pL[(rh * 16 + r) * 32 + kq * 4];
                acc[r] += pv.x * e0 + pv.y * e1 + pv.z * e2 + pv.w * e3;
            }
        }
    }
#pragma unroll
    for (int r = 0; r < 16; ++r)
        atomicAdd(&exbuf[(rt0 + rh * 16 + r) * 128 + d], acc[r]);
}

__global__ __launch_bounds__(128) void uecomb_k(const float* __restrict__ x, const int* __restrict__ m_mask,
                                                const float* __restrict__ exbuf, float* __restrict__ ue) {
    int row = blockIdx.x, t = threadIdx.x;
    bool mm = m_mask[row] != 0;
    ue[row * 128 + t] = mm ? exbuf[row * 128 + t] : x[row * 128 + t];
}

// U2[(z*2+k)][i][(b*8+c)] = sum_a qz[z,i,a] T[k][a][(b,c)]
// W2[(z*2+k)][j][(a*8+c)] = sum_b qz[z,j,b] Tt[k][b][(a,c)]
__global__ __launch_bounds__(256) void uwgemm_k(const float* __restrict__ qz, const float* __restrict__ T,
                                                const float* __restrict__ Tt, float* __restrict__ U2,
                                                float* __restrict__ W2) {
    int t = threadIdx.x;
    int by = blockIdx.y;            // 16: uw(2) x z(4) x k(2)
    int uw = by >> 3, z = (by >> 1) & 3, k = by & 1;
    int bx = blockIdx.x;            // 32: mt(8) x nt(4)
    int m0 = (bx >> 2) * 16, n = (bx & 3) * 256 + t;
    const float* A = qz + z * 16384;
    const float* Bm = (uw ? Tt : T) + k * 131072;
    float* Cm = (uw ? W2 : U2) + (z * 2 + k) * 131072;
    __shared__ float aL[2048];
    for (int idx = t; idx < 2048; idx += 256)
        aL[idx] = A[(m0 + (idx >> 7)) * 128 + (idx & 127)];
    __syncthreads();
    float acc[16];
#pragma unroll
    for (int m = 0; m < 16; ++m) acc[m] = 0.f;
    for (int kq = 0; kq < 32; ++kq) {
        float b0 = Bm[(kq * 4 + 0) * 1024 + n];
        float b1 = Bm[(kq * 4 + 1) * 1024 + n];
        float b2 = Bm[(kq * 4 + 2) * 1024 + n];
        float b3 = Bm[(kq * 4 + 3) * 1024 + n];
#pragma unroll
        for (int m = 0; m < 16; ++m) {
            const float4 aq = *(const float4*)&aL[m * 128 + kq * 4];
            acc[m] += aq.x * b0 + aq.y * b1 + aq.z * b2 + aq.w * b3;
        }
    }
#pragma unroll
    for (int m = 0; m < 16; ++m)
        Cm[(m0 + m) * 1024 + n] = acc[m];
}

// q_hn[z,c,i,:] = softmax_j( F ) with diag/invalid = -NEG;  also writes transposed copy
__global__ __launch_bounds__(256) void qhn_k(const float* __restrict__ qz, const float* __restrict__ U2,
                                             const int* __restrict__ mask, float* __restrict__ qhn,
                                             float* __restrict__ qhnT) {
    int bid = blockIdx.x;
    int z = bid >> 7, i = bid & 127;
    int t = threadIdx.x;
    __shared__ float uL[2048];
    __shared__ float qzC[128 * 33];
    __shared__ float fL[1024];
    {
        const float* ub = U2 + z * 262144 + i * 1024;
        for (int idx = t; idx < 2048; idx += 256) {
            int k = idx >> 10, bc = idx & 1023;
            uL[idx] = ub[k * 131072 + bc];
        }
    }
    int j = t & 127, ch = t >> 7;
    int kSel = (j > i) ? 0 : 1;
    const int ubase = kSel * 1024 + ch;
    float acc4[4] = {0.f, 0.f, 0.f, 0.f};
    for (int bcn = 0; bcn < 4; ++bcn) {
        __syncthreads();
        for (int idx = t; idx < 4096; idx += 256) {
            int jj = idx >> 5, bb = idx & 31;
            qzC[jj * 33 + bb] = qz[z * 16384 + jj * 128 + bcn * 32 + bb];
        }
        __syncthreads();
#pragma unroll 8
        for (int bb = 0; bb < 32; ++bb) {
            float qv = qzC[j * 33 + bb];
            int b8 = (bcn * 32 + bb) * 8;
            acc4[0] += uL[ubase + b8] * qv;
            acc4[1] += uL[ubase + b8 + 2] * qv;
            acc4[2] += uL[ubase + b8 + 4] * qv;
            acc4[3] += uL[ubase + b8 + 6] * qv;
        }
    }
    bool vi = mask[z * 128 + i] != 0;
    bool vj = mask[z * 128 + j] != 0;
#pragma unroll
    for (int g = 0; g < 4; ++g) {
        float F = acc4[g];
        if (j == i) F -= NEGC;
        if (!vi || !vj) F = -NEGC;
        fL[(2 * g + ch) * 128 + j] = F;
    }
    __syncthreads();
    int c = t >> 5, lane = t & 31;
    float mval = -3.4e38f;
#pragma unroll
    for (int q = 0; q < 4; ++q) mval = fmaxf(mval, fL[c * 128 + lane + q * 32]);
    for (int off = 16; off; off >>= 1) mval = fmaxf(mval, __shfl_xor(mval, off, 32));
    float ssum = 0.f;
#pragma unroll
    for (int q = 0; q < 4; ++q) ssum += __expf(fL[c * 128 + lane + q * 32] - mval);
    for (int off = 16; off; off >>= 1) ssum += __shfl_xor(ssum, off, 32);
    float inv = 1.f / ssum;
#pragma unroll
    for (int q = 0; q < 4; ++q) {
        int j2 = lane + q * 32;
        float val = __expf(fL[c * 128 + j2] - mval) * inv;
        qhn[((z * 8 + c) * 128 + i) * 128 + j2] = val;
        qhnT[((z * 8 + c) * 128 + j2) * 128 + i] = val;
    }
}

// mode 0: G1[z,i,a] = sum_{c,s} hn[c,i,s] * W2[k(s,i)][s][(a,c)]   (k=0 iff s>i)
// mode 1: G2[z,j,b] = sum_{c,s} hn[c,s,j] * U2[k(s,j)][s][(b,c)]   (k=0 iff s<j)
__global__ __launch_bounds__(256) void gkern_k(const float* __restrict__ qhn, const float* __restrict__ qhnT,
                                               const float* __restrict__ U2, const float* __restrict__ W2,
                                               float* __restrict__ g1, float* __restrict__ g2) {
    int mode = blockIdx.y;
    int z = blockIdx.x >> 5;
    int t0 = (blockIdx.x & 31) * 4;
    int t = threadIdx.x;
    __shared__ float hnL[4 * 8 * 128];   // [ii][c][s]
    __shared__ float red[2 * 4 * 128];
    const float* hsrc = mode ? qhnT : qhn;
    for (int idx = t; idx < 4096; idx += 256) {
        int ii = idx >> 10, rem = idx & 1023;
        int c = rem >> 7, s = rem & 127;
        hnL[idx] = hsrc[((z * 8 + c) * 128 + t0 + ii) * 128 + s];
    }
    __syncthreads();
    int a = t & 127, ch = t >> 7, cb = ch * 4;
    const float* M0 = (mode ? U2 : W2) + z * 262144;
    const float* M1 = M0 + 131072;
    float acc[4] = {0.f, 0.f, 0.f, 0.f};
    const float4 zero4 = {0.f, 0.f, 0.f, 0.f};
    for (int s = 0; s < 128; ++s) {
        bool n0 = mode ? (s < t0 + 3) : (s > t0);
        bool n1 = mode ? (s > t0) : (s < t0 + 3);
        float4 w0 = n0 ? *(const float4*)&M0[s * 1024 + a * 8 + cb] : zero4;
        float4 w1 = n1 ? *(const float4*)&M1[s * 1024 + a * 8 + cb] : zero4;
#pragma unroll
        for (int ii = 0; ii < 4; ++ii) {
            int o = t0 + ii;
            bool u0 = mode ? (s < o) : (s > o);
            float4 wv = u0 ? w0 : w1;
            const float* hrow = &hnL[(ii * 8 + cb) * 128 + s];
            acc[ii] += hrow[0] * wv.x + hrow[128] * wv.y + hrow[256] * wv.z + hrow[384] * wv.w;
        }
    }
#pragma unroll
    for (int ii = 0; ii < 4; ++ii) red[(ch * 4 + ii) * 128 + a] = acc[ii];
    __syncthreads();
    if (ch == 0) {
        float* Gout = mode ? g2 : g1;
#pragma unroll
        for (int ii = 0; ii < 4; ++ii) {
            float v = red[ii * 128 + t] + red[(4 + ii) * 128 + t];
            Gout[(z * 128 + t0 + ii) * 128 + t] = v;
        }
    }
}

// qz = softmax_D(ue + g1 + g2) * keep
__global__ __launch_bounds__(64) void zupd_k(const float* __restrict__ ue, const float* __restrict__ g1,
                                             const float* __restrict__ g2, const int* __restrict__ mask,
                                             float* __restrict__ qz) {
    int row = blockIdx.x, t = threadIdx.x;
    float keepv = mask[row] ? 1.f : 0.f;
    int b = row * 128;
    float v0 = ue[b + t] + g1[b + t] + g2[b + t];
    float v1 = ue[b + t + 64] + g1[b + t + 64] + g2[b + t + 64];
    float m = fmaxf(v0, v1);
    for (int off = 32; off; off >>= 1) m = fmaxf(m, __shfl_xor(m, off));
    float e0 = __expf(v0 - m), e1 = __expf(v1 - m);
    float s = e0 + e1;
    for (int off = 32; off; off >>= 1) s += __shfl_xor(s, off);
    float inv = keepv / s;
    qz[b + t] = e0 * inv;
    qz[b + t + 64] = e1 * inv;
}

// out[row][v] = sum_a qz[row][a] * E[v][a]
__global__ __launch_bounds__(256) void msgx_k(const float* __restrict__ qz, const float* __restrict__ E,
                                              float* __restrict__ out) {
    int t = threadIdx.x;
    int rt0 = blockIdx.x * 64;
    int vbase = blockIdx.y * 256;
    __shared__ float qzL[64 * 128];
    __shared__ float eL[128 * 33];
    for (int idx = t; idx < 8192; idx += 256)
        qzL[idx] = qz[rt0 * 128 + idx];
    int v_l = t & 31, rg = t >> 5;
    int r0 = rg * 8;
    for (int stage = 0; stage < 8; ++stage) {
        int vb = vbase + stage * 32;
        __syncthreads();
        for (int idx = t; idx < 4096; idx += 256) {
            int vv = idx >> 7, aa = idx & 127;
            eL[aa * 33 + vv] = E[(vb + vv) * 128 + aa];
        }
        __syncthreads();
        float acc[8] = {0, 0, 0, 0, 0, 0, 0, 0};
        for (int a4 = 0; a4 < 32; ++a4) {
            float e0 = eL[(a4 * 4 + 0) * 33 + v_l];
            float e1 = eL[(a4 * 4 + 1) * 33 + v_l];
            float e2 = eL[(a4 * 4 + 2) * 33 + v_l];
            float e3 = eL[(a4 * 4 + 3) * 33 + v_l];
#pragma unroll
            for (int rr = 0; rr < 8; ++rr) {
                const float4 q = *(const float4*)&qzL[(r0 + rr) * 128 + a4 * 4];
                acc[rr] += q.x * e0 + q.y * e1 + q.z * e2 + q.w * e3;
            }
        }
#pragma unroll
        for (int rr = 0; rr < 8; ++rr)
            out[(size_t)(rt0 + r0 + rr) * V_ + vb + v_l] = acc[rr];
    }
}

extern "C" void kernel_launch(void* const* d_in, const int* in_sizes, int n_in,
                              void* d_out, int out_size, void* d_ws, size_t ws_size,
                              hipStream_t stream) {
    const float* x     = (const float*)d_in[0];   // [B,L,D]
    const int*   mask  = (const int*)d_in[1];     // [B,L]
    const float* E     = (const float*)d_in[2];   // [V,D]
    const int*   mmask = (const int*)d_in[3];     // [B,L]
    const float* T     = (const float*)d_in[4];   // [2,D,D,H]
    float* out = (float*)d_out;                   // [B,L,V]

    float* w = (float*)d_ws;
    float* meansum = w;                 // 128
    float* ue      = w + 128;           // 65536
    float* qz      = ue + 65536;        // 65536
    float* exbuf   = qz + 65536;        // 65536
    float* g1      = exbuf + 65536;     // 65536
    float* g2      = g1 + 65536;        // 65536
    float* rowm    = g2 + 65536;        // 512
    float* rowinv  = rowm + 512;        // 512
    float* Tt      = rowinv + 512;      // 262144
    float* U2      = Tt + 262144;       // 1048576
    float* W2      = U2 + 1048576;      // 1048576
    float* qhn     = W2 + 1048576;      // 524288
    float* qhnT    = qhn + 524288;      // 524288  -> total ~14.3 MB

    hipMemsetAsync(meansum, 0, 128 * sizeof(float), stream);
    colsum_k<<<125, 256, 0, stream>>>(E, meansum);
    transT_k<<<256, 256, 0, stream>>>(T, Tt);
    init_k<<<512, 64, 0, stream>>>(x, mask, mmask, meansum, ue, qz);

    for (int it = 0; it < 4; ++it) {
        if (it) {
            rowstat_k<<<512, 256, 0, stream>>>(out, rowm, rowinv);
            hipMemsetAsync(exbuf, 0, 65536 * sizeof(float), stream);
            exgemm_k<<<dim3(16, 100), 256, 0, stream>>>(out, E, rowm, rowinv, exbuf);
            uecomb_k<<<512, 128, 0, stream>>>(x, mmask, exbuf, ue);
        }
        uwgemm_k<<<dim3(32, 16), 256, 0, stream>>>(qz, T, Tt, U2, W2);
        qhn_k<<<512, 256, 0, stream>>>(qz, U2, mask, qhn, qhnT);
        gkern_k<<<dim3(128, 2), 256, 0, stream>>>(qhn, qhnT, U2, W2, g1, g2);
        zupd_k<<<512, 64, 0, stream>>>(ue, g1, g2, mask, qz);
        msgx_k<<<dim3(8, 125), 256, 0, stream>>>(qz, E, out);
    }
}

// Round 3
// 1230.401 us; speedup vs baseline: 1.8301x; 1.3375x over previous
//
#include <hip/hip_runtime.h>
#include <math.h>

#define L_ 128
#define D_ 128
#define H_ 8
#define V_ 32000
#define NEGC 1e9f

typedef short short8 __attribute__((ext_vector_type(8)));
typedef float f32x4 __attribute__((ext_vector_type(4)));

__device__ __forceinline__ unsigned short f2bf(float x) {
    unsigned int u = __float_as_uint(x);
    unsigned int r = (u + 0x7fff + ((u >> 16) & 1)) >> 16;
    return (unsigned short)r;
}

// ---------- one-time precompute ----------

// meansum[d] = sum_v E[v][d]
__global__ __launch_bounds__(256) void colsum_k(const float* __restrict__ E, float* __restrict__ meansum) {
    int t = threadIdx.x;
    int d = t & 127, h = t >> 7;
    int v0 = blockIdx.x * 256;
    float s = 0.f;
    for (int p = 0; p < 128; ++p)
        s += E[(v0 + h + 2 * p) * 128 + d];
    __shared__ float red[256];
    red[t] = s;
    __syncthreads();
    if (h == 0) atomicAdd(&meansum[d], red[d] + red[128 + d]);
}

// E (fp32, [V,128]) -> Eb (bf16)
__global__ __launch_bounds__(256) void cvtE_k(const float* __restrict__ E, unsigned short* __restrict__ Eb) {
    int i = blockIdx.x * 256 + threadIdx.x;   // x4 floats
    float4 v = ((const float4*)E)[i];
    ushort4 o;
    o.x = f2bf(v.x); o.y = f2bf(v.y); o.z = f2bf(v.z); o.w = f2bf(v.w);
    ((ushort4*)Eb)[i] = o;
}

// Tt[k][b][a*8+c] = T[k][a][b*8+c]   (transpose over (a,b), keep c)
__global__ __launch_bounds__(256) void transT_k(const float* __restrict__ T, float* __restrict__ Tt) {
    for (int q = 0; q < 4; ++q) {
        int id = blockIdx.x * 1024 + q * 256 + threadIdx.x;   // 0..262143
        int k = id >> 17;
        int rem = id & 131071;
        int a = rem >> 10;
        int bc = rem & 1023;
        int b = bc >> 3, c = bc & 7;
        Tt[k * 131072 + b * 1024 + a * 8 + c] = T[id];
    }
}

// ue = select(mm, colmean, x);  qz = softmax_D(ue*keep)*keep  (+ bf16 copy)
__global__ __launch_bounds__(64) void init_k(const float* __restrict__ x, const int* __restrict__ mask,
                                             const int* __restrict__ m_mask, const float* __restrict__ meansum,
                                             float* __restrict__ ue, float* __restrict__ qz,
                                             unsigned short* __restrict__ qzb) {
    int row = blockIdx.x, t = threadIdx.x;
    float keepv = mask[row] ? 1.f : 0.f;
    bool mm = m_mask[row] != 0;
    float pre0 = meansum[t] * (1.f / 32000.f);
    float pre1 = meansum[t + 64] * (1.f / 32000.f);
    float u0 = mm ? pre0 : x[row * 128 + t];
    float u1 = mm ? pre1 : x[row * 128 + t + 64];
    ue[row * 128 + t] = u0;
    ue[row * 128 + t + 64] = u1;
    float sv0 = u0 * keepv, sv1 = u1 * keepv;
    float m = fmaxf(sv0, sv1);
    for (int off = 32; off; off >>= 1) m = fmaxf(m, __shfl_xor(m, off));
    float e0 = __expf(sv0 - m), e1 = __expf(sv1 - m);
    float s = e0 + e1;
    for (int off = 32; off; off >>= 1) s += __shfl_xor(s, off);
    float inv = keepv / s;
    float q0 = e0 * inv, q1 = e1 * inv;
    qz[row * 128 + t] = q0;
    qz[row * 128 + t + 64] = q1;
    qzb[row * 128 + t] = f2bf(q0);
    qzb[row * 128 + t + 64] = f2bf(q1);
}

// ---------- per-iteration kernels ----------

// per-row max & 1/sumexp over V of q_x
__global__ __launch_bounds__(256) void rowstat_k(const float* __restrict__ qx, float* __restrict__ rowm,
                                                 float* __restrict__ rowinv) {
    int row = blockIdx.x, t = threadIdx.x;
    const float* p = qx + (size_t)row * V_;
    float m = -3.4e38f, s = 0.f;
    for (int v = t; v < V_; v += 256) {
        float xv = p[v];
        if (xv <= m) s += __expf(xv - m);
        else { s = s * __expf(m - xv) + 1.f; m = xv; }
    }
    for (int off = 32; off; off >>= 1) {
        float m2 = __shfl_xor(m, off);
        float s2 = __shfl_xor(s, off);
        float M = fmaxf(m, m2);
        s = s * __expf(m - M) + s2 * __expf(m2 - M);
        m = M;
    }
    __shared__ float sm[4], ss[4];
    int w = t >> 6;
    if ((t & 63) == 0) { sm[w] = m; ss[w] = s; }
    __syncthreads();
    if (t == 0) {
        float M = sm[0], S = ss[0];
        for (int i = 1; i < 4; ++i) {
            float M2 = fmaxf(M, sm[i]);
            S = S * __expf(M - M2) + ss[i] * __expf(sm[i] - M2);
            M = M2;
        }
        rowm[row] = M;
        rowinv[row] = 1.f / S;
    }
}

// exbuf[row][d] += sum_k softmax(qx)[row][k] * E[k][d]   (split-K atomics)
__global__ __launch_bounds__(256) void exgemm_k(const float* __restrict__ qx, const float* __restrict__ E,
                                                const float* __restrict__ rowm, const float* __restrict__ rowinv,
                                                float* __restrict__ exbuf) {
    int t = threadIdx.x;
    int d = t & 127, rh = t >> 7;
    int rt0 = blockIdx.x * 32;
    int k0 = blockIdx.y * 320;
    __shared__ float pL[32 * 32];
    float acc[16];
#pragma unroll
    for (int r = 0; r < 16; ++r) acc[r] = 0.f;
    for (int kt = 0; kt < 10; ++kt) {
        int kk0 = k0 + kt * 32;
        __syncthreads();
        for (int idx = t; idx < 1024; idx += 256) {
            int r = idx >> 5, kk = idx & 31;
            int row = rt0 + r;
            pL[idx] = __expf(qx[(size_t)row * V_ + kk0 + kk] - rowm[row]) * rowinv[row];
        }
        __syncthreads();
#pragma unroll
        for (int kq = 0; kq < 8; ++kq) {
            float e0 = E[(kk0 + kq * 4 + 0) * 128 + d];
            float e1 = E[(kk0 + kq * 4 + 1) * 128 + d];
            float e2 = E[(kk0 + kq * 4 + 2) * 128 + d];
            float e3 = E[(kk0 + kq * 4 + 3) * 128 + d];
#pragma unroll
            for (int r = 0; r < 16; ++r) {
                const float4 pv = *(const float4*)&pL[(rh * 16 + r) * 32 + kq * 4];
                acc[r] += pv.x * e0 + pv.y * e1 + pv.z * e2 + pv.w * e3;
            }
        }
    }
#pragma unroll
    for (int r = 0; r < 16; ++r)
        atomicAdd(&exbuf[(rt0 + rh * 16 + r) * 128 + d], acc[r]);
}

__global__ __launch_bounds__(128) void uecomb_k(const float* __restrict__ x, const int* __restrict__ m_mask,
                                                const float* __restrict__ exbuf, float* __restrict__ ue) {
    int row = blockIdx.x, t = threadIdx.x;
    bool mm = m_mask[row] != 0;
    ue[row * 128 + t] = mm ? exbuf[row * 128 + t] : x[row * 128 + t];
}

// U2[(z*2+k)][i][(b*8+c)] = sum_a qz[z,i,a] T[k][a][(b,c)]
// W2[(z*2+k)][j][(a*8+c)] = sum_b qz[z,j,b] Tt[k][b][(a,c)]
__global__ __launch_bounds__(256) void uwgemm_k(const float* __restrict__ qz, const float* __restrict__ T,
                                                const float* __restrict__ Tt, float* __restrict__ U2,
                                                float* __restrict__ W2) {
    int t = threadIdx.x;
    int by = blockIdx.y;            // 16: uw(2) x z(4) x k(2)
    int uw = by >> 3, z = (by >> 1) & 3, k = by & 1;
    int bx = blockIdx.x;            // 32: mt(8) x nt(4)
    int m0 = (bx >> 2) * 16, n = (bx & 3) * 256 + t;
    const float* A = qz + z * 16384;
    const float* Bm = (uw ? Tt : T) + k * 131072;
    float* Cm = (uw ? W2 : U2) + (z * 2 + k) * 131072;
    __shared__ float aL[2048];
    for (int idx = t; idx < 2048; idx += 256)
        aL[idx] = A[(m0 + (idx >> 7)) * 128 + (idx & 127)];
    __syncthreads();
    float acc[16];
#pragma unroll
    for (int m = 0; m < 16; ++m) acc[m] = 0.f;
    for (int kq = 0; kq < 32; ++kq) {
        float b0 = Bm[(kq * 4 + 0) * 1024 + n];
        float b1 = Bm[(kq * 4 + 1) * 1024 + n];
        float b2 = Bm[(kq * 4 + 2) * 1024 + n];
        float b3 = Bm[(kq * 4 + 3) * 1024 + n];
#pragma unroll
        for (int m = 0; m < 16; ++m) {
            const float4 aq = *(const float4*)&aL[m * 128 + kq * 4];
            acc[m] += aq.x * b0 + aq.y * b1 + aq.z * b2 + aq.w * b3;
        }
    }
#pragma unroll
    for (int m = 0; m < 16; ++m)
        Cm[(m0 + m) * 1024 + n] = acc[m];
}

// q_hn[z,c,i,:] = softmax_j( F ) with diag/invalid = -NEG;  also writes transposed copy
__global__ __launch_bounds__(256) void qhn_k(const float* __restrict__ qz, const float* __restrict__ U2,
                                             const int* __restrict__ mask, float* __restrict__ qhn,
                                             float* __restrict__ qhnT) {
    int bid = blockIdx.x;
    int z = bid >> 7, i = bid & 127;
    int t = threadIdx.x;
    __shared__ float uL[2048];
    __shared__ float qzC[128 * 33];
    __shared__ float fL[1024];
    {
        const float* ub = U2 + z * 262144 + i * 1024;
        for (int idx = t; idx < 2048; idx += 256) {
            int k = idx >> 10, bc = idx & 1023;
            uL[idx] = ub[k * 131072 + bc];
        }
    }
    int j = t & 127, ch = t >> 7;
    int kSel = (j > i) ? 0 : 1;
    const int ubase = kSel * 1024 + ch;
    float acc4[4] = {0.f, 0.f, 0.f, 0.f};
    for (int bcn = 0; bcn < 4; ++bcn) {
        __syncthreads();
        for (int idx = t; idx < 4096; idx += 256) {
            int jj = idx >> 5, bb = idx & 31;
            qzC[jj * 33 + bb] = qz[z * 16384 + jj * 128 + bcn * 32 + bb];
        }
        __syncthreads();
#pragma unroll 8
        for (int bb = 0; bb < 32; ++bb) {
            float qv = qzC[j * 33 + bb];
            int b8 = (bcn * 32 + bb) * 8;
            acc4[0] += uL[ubase + b8] * qv;
            acc4[1] += uL[ubase + b8 + 2] * qv;
            acc4[2] += uL[ubase + b8 + 4] * qv;
            acc4[3] += uL[ubase + b8 + 6] * qv;
        }
    }
    bool vi = mask[z * 128 + i] != 0;
    bool vj = mask[z * 128 + j] != 0;
#pragma unroll
    for (int g = 0; g < 4; ++g) {
        float F = acc4[g];
        if (j == i) F -= NEGC;
        if (!vi || !vj) F = -NEGC;
        fL[(2 * g + ch) * 128 + j] = F;
    }
    __syncthreads();
    int c = t >> 5, lane = t & 31;
    float mval = -3.4e38f;
#pragma unroll
    for (int q = 0; q < 4; ++q) mval = fmaxf(mval, fL[c * 128 + lane + q * 32]);
    for (int off = 16; off; off >>= 1) mval = fmaxf(mval, __shfl_xor(mval, off, 32));
    float ssum = 0.f;
#pragma unroll
    for (int q = 0; q < 4; ++q) ssum += __expf(fL[c * 128 + lane + q * 32] - mval);
    for (int off = 16; off; off >>= 1) ssum += __shfl_xor(ssum, off, 32);
    float inv = 1.f / ssum;
#pragma unroll
    for (int q = 0; q < 4; ++q) {
        int j2 = lane + q * 32;
        float val = __expf(fL[c * 128 + j2] - mval) * inv;
        qhn[((z * 8 + c) * 128 + i) * 128 + j2] = val;
        qhnT[((z * 8 + c) * 128 + j2) * 128 + i] = val;
    }
}

// mode 0: G1[z,i,a] = sum_{c,s} hn[c,i,s] * W2[k(s,i)][s][(a,c)]   (k=0 iff s>i)
// mode 1: G2[z,j,b] = sum_{c,s} hn[c,s,j] * U2[k(s,j)][s][(b,c)]   (k=0 iff s<j)
__global__ __launch_bounds__(256) void gkern_k(const float* __restrict__ qhn, const float* __restrict__ qhnT,
                                               const float* __restrict__ U2, const float* __restrict__ W2,
                                               float* __restrict__ g1, float* __restrict__ g2) {
    int mode = blockIdx.y;
    int z = blockIdx.x >> 5;
    int t0 = (blockIdx.x & 31) * 4;
    int t = threadIdx.x;
    __shared__ float hnL[4 * 8 * 128];   // [ii][c][s]
    __shared__ float red[2 * 4 * 128];
    const float* hsrc = mode ? qhnT : qhn;
    for (int idx = t; idx < 4096; idx += 256) {
        int ii = idx >> 10, rem = idx & 1023;
        int c = rem >> 7, s = rem & 127;
        hnL[idx] = hsrc[((z * 8 + c) * 128 + t0 + ii) * 128 + s];
    }
    __syncthreads();
    int a = t & 127, ch = t >> 7, cb = ch * 4;
    const float* M0 = (mode ? U2 : W2) + z * 262144;
    const float* M1 = M0 + 131072;
    float acc[4] = {0.f, 0.f, 0.f, 0.f};
    const float4 zero4 = {0.f, 0.f, 0.f, 0.f};
    for (int s = 0; s < 128; ++s) {
        bool n0 = mode ? (s < t0 + 3) : (s > t0);
        bool n1 = mode ? (s > t0) : (s < t0 + 3);
        float4 w0 = n0 ? *(const float4*)&M0[s * 1024 + a * 8 + cb] : zero4;
        float4 w1 = n1 ? *(const float4*)&M1[s * 1024 + a * 8 + cb] : zero4;
#pragma unroll
        for (int ii = 0; ii < 4; ++ii) {
            int o = t0 + ii;
            bool u0 = mode ? (s < o) : (s > o);
            float4 wv = u0 ? w0 : w1;
            const float* hrow = &hnL[(ii * 8 + cb) * 128 + s];
            acc[ii] += hrow[0] * wv.x + hrow[128] * wv.y + hrow[256] * wv.z + hrow[384] * wv.w;
        }
    }
#pragma unroll
    for (int ii = 0; ii < 4; ++ii) red[(ch * 4 + ii) * 128 + a] = acc[ii];
    __syncthreads();
    if (ch == 0) {
        float* Gout = mode ? g2 : g1;
#pragma unroll
        for (int ii = 0; ii < 4; ++ii) {
            float v = red[ii * 128 + t] + red[(4 + ii) * 128 + t];
            Gout[(z * 128 + t0 + ii) * 128 + t] = v;
        }
    }
}

// qz = softmax_D(ue + g1 + g2) * keep   (+ bf16 copy)
__global__ __launch_bounds__(64) void zupd_k(const float* __restrict__ ue, const float* __restrict__ g1,
                                             const float* __restrict__ g2, const int* __restrict__ mask,
                                             float* __restrict__ qz, unsigned short* __restrict__ qzb) {
    int row = blockIdx.x, t = threadIdx.x;
    float keepv = mask[row] ? 1.f : 0.f;
    int b = row * 128;
    float v0 = ue[b + t] + g1[b + t] + g2[b + t];
    float v1 = ue[b + t + 64] + g1[b + t + 64] + g2[b + t + 64];
    float m = fmaxf(v0, v1);
    for (int off = 32; off; off >>= 1) m = fmaxf(m, __shfl_xor(m, off));
    float e0 = __expf(v0 - m), e1 = __expf(v1 - m);
    float s = e0 + e1;
    for (int off = 32; off; off >>= 1) s += __shfl_xor(s, off);
    float inv = keepv / s;
    float q0 = e0 * inv, q1 = e1 * inv;
    qz[b + t] = q0;
    qz[b + t + 64] = q1;
    qzb[b + t] = f2bf(q0);
    qzb[b + t + 64] = f2bf(q1);
}

// out[row][v] = sum_a qz[row][a] * E[v][a]   — bf16 MFMA NT-GEMM
// block: 64 rows x 256 cols, 4 waves each owning 64 cols; grid (8, 125)
__global__ __launch_bounds__(256) void msgx_mfma_k(const unsigned short* __restrict__ qzb,
                                                   const unsigned short* __restrict__ Eb,
                                                   float* __restrict__ out) {
    int t = threadIdx.x;
    int w = t >> 6, lane = t & 63;
    int nloc = lane & 15, half = lane >> 4;
    int rt0 = blockIdx.x * 64;
    int cb0 = blockIdx.y * 256 + w * 64;
    short8 afr[4][4];   // [rowtile][kstep]
#pragma unroll
    for (int r = 0; r < 4; ++r)
#pragma unroll
        for (int s = 0; s < 4; ++s)
            afr[r][s] = *(const short8*)&qzb[(rt0 + r * 16 + nloc) * 128 + s * 32 + half * 8];
    f32x4 acc[4][4];    // [rowtile][coltile]
#pragma unroll
    for (int r = 0; r < 4; ++r)
#pragma unroll
        for (int ct = 0; ct < 4; ++ct)
            acc[r][ct] = (f32x4){0.f, 0.f, 0.f, 0.f};
#pragma unroll
    for (int ct = 0; ct < 4; ++ct) {
#pragma unroll
        for (int s = 0; s < 4; ++s) {
            short8 bfr = *(const short8*)&Eb[(size_t)(cb0 + ct * 16 + nloc) * 128 + s * 32 + half * 8];
#pragma unroll
            for (int r = 0; r < 4; ++r)
                acc[r][ct] = __builtin_amdgcn_mfma_f32_16x16x32_bf16(afr[r][s], bfr, acc[r][ct], 0, 0, 0);
        }
    }
#pragma unroll
    for (int r = 0; r < 4; ++r)
#pragma unroll
        for (int ct = 0; ct < 4; ++ct) {
            int col = cb0 + ct * 16 + nloc;
#pragma unroll
            for (int reg = 0; reg < 4; ++reg) {
                int row = rt0 + r * 16 + half * 4 + reg;
                out[(size_t)row * V_ + col] = acc[r][ct][reg];
            }
        }
}

extern "C" void kernel_launch(void* const* d_in, const int* in_sizes, int n_in,
                              void* d_out, int out_size, void* d_ws, size_t ws_size,
                              hipStream_t stream) {
    const float* x     = (const float*)d_in[0];   // [B,L,D]
    const int*   mask  = (const int*)d_in[1];     // [B,L]
    const float* E     = (const float*)d_in[2];   // [V,D]
    const int*   mmask = (const int*)d_in[3];     // [B,L]
    const float* T     = (const float*)d_in[4];   // [2,D,D,H]
    float* out = (float*)d_out;                   // [B,L,V]

    float* w = (float*)d_ws;
    float* meansum = w;                 // 128
    float* ue      = w + 128;           // 65536
    float* qz      = ue + 65536;        // 65536
    float* exbuf   = qz + 65536;        // 65536
    float* g1      = exbuf + 65536;     // 65536
    float* g2      = g1 + 65536;        // 65536
    float* rowm    = g2 + 65536;        // 512
    float* rowinv  = rowm + 512;        // 512
    float* Tt      = rowinv + 512;      // 262144
    float* U2      = Tt + 262144;       // 1048576
    float* W2      = U2 + 1048576;      // 1048576
    float* qhn     = W2 + 1048576;      // 524288
    float* qhnT    = qhn + 524288;      // 524288
    unsigned short* qzb = (unsigned short*)(qhnT + 524288);  // 65536 ushort = 32768 floats
    unsigned short* Eb  = (unsigned short*)(qhnT + 524288 + 32768); // 4,096,000 ushort (~8.2 MB)

    hipMemsetAsync(meansum, 0, 128 * sizeof(float), stream);
    colsum_k<<<125, 256, 0, stream>>>(E, meansum);
    cvtE_k<<<4000, 256, 0, stream>>>(E, Eb);
    transT_k<<<256, 256, 0, stream>>>(T, Tt);
    init_k<<<512, 64, 0, stream>>>(x, mask, mmask, meansum, ue, qz, qzb);

    for (int it = 0; it < 4; ++it) {
        if (it) {
            rowstat_k<<<512, 256, 0, stream>>>(out, rowm, rowinv);
            hipMemsetAsync(exbuf, 0, 65536 * sizeof(float), stream);
            exgemm_k<<<dim3(16, 100), 256, 0, stream>>>(out, E, rowm, rowinv, exbuf);
            uecomb_k<<<512, 128, 0, stream>>>(x, mmask, exbuf, ue);
        }
        uwgemm_k<<<dim3(32, 16), 256, 0, stream>>>(qz, T, Tt, U2, W2);
        qhn_k<<<512, 256, 0, stream>>>(qz, U2, mask, qhn, qhnT);
        gkern_k<<<dim3(128, 2), 256, 0, stream>>>(qhn, qhnT, U2, W2, g1, g2);
        zupd_k<<<512, 64, 0, stream>>>(ue, g1, g2, mask, qz, qzb);
        msgx_mfma_k<<<dim3(8, 125), 256, 0, stream>>>(qzb, Eb, out);
    }
}

// Round 4
// 1039.869 us; speedup vs baseline: 2.1654x; 1.1832x over previous
//
#include <hip/hip_runtime.h>
#include <math.h>

#define L_ 128
#define D_ 128
#define H_ 8
#define V_ 32000
#define NEGC 1e9f

typedef short short8 __attribute__((ext_vector_type(8)));
typedef float f32x4 __attribute__((ext_vector_type(4)));

__device__ __forceinline__ unsigned short f2bf(float x) {
    unsigned int u = __float_as_uint(x);
    unsigned int r = (u + 0x7fff + ((u >> 16) & 1)) >> 16;
    return (unsigned short)r;
}

// ---------- one-time precompute ----------

// meansum[d] = sum_v E[v][d]
__global__ __launch_bounds__(256) void colsum_k(const float* __restrict__ E, float* __restrict__ meansum) {
    int t = threadIdx.x;
    int d = t & 127, h = t >> 7;
    int v0 = blockIdx.x * 256;
    float s = 0.f;
    for (int p = 0; p < 128; ++p)
        s += E[(v0 + h + 2 * p) * 128 + d];
    __shared__ float red[256];
    red[t] = s;
    __syncthreads();
    if (h == 0) atomicAdd(&meansum[d], red[d] + red[128 + d]);
}

// E (fp32, [V,128]) -> Eb (bf16, row-major)
__global__ __launch_bounds__(256) void cvtE_k(const float* __restrict__ E, unsigned short* __restrict__ Eb) {
    int i = blockIdx.x * 256 + threadIdx.x;   // x4 floats
    float4 v = ((const float4*)E)[i];
    ushort4 o;
    o.x = f2bf(v.x); o.y = f2bf(v.y); o.z = f2bf(v.z); o.w = f2bf(v.w);
    ((ushort4*)Eb)[i] = o;
}

// Et[d][v] = bf16(E[v][d])  — LDS-tiled transpose, 256 v x 128 d per block
__global__ __launch_bounds__(256) void transEt_k(const float* __restrict__ E, unsigned short* __restrict__ Et) {
    __shared__ unsigned short tile[128][68];
    int t = threadIdx.x;
    int v0 = blockIdx.x * 256;
    for (int sub = 0; sub < 4; ++sub) {
        int vs = v0 + sub * 64;
        __syncthreads();
#pragma unroll
        for (int i = 0; i < 8; ++i) {
            int idx = i * 256 + t;          // 2048 float4 = 64 v x 128 d
            int v = idx >> 5;
            int d4 = (idx & 31) * 4;
            float4 val = *(const float4*)&E[(size_t)(vs + v) * 128 + d4];
            tile[d4 + 0][v] = f2bf(val.x);
            tile[d4 + 1][v] = f2bf(val.y);
            tile[d4 + 2][v] = f2bf(val.z);
            tile[d4 + 3][v] = f2bf(val.w);
        }
        __syncthreads();
#pragma unroll
        for (int i = 0; i < 8; ++i) {
            int idx = i * 256 + t;          // 2048 ushort4 = 128 d x 64 v
            int d = idx >> 4;
            int vv = (idx & 15) * 4;
            ushort4 o;
            o.x = tile[d][vv]; o.y = tile[d][vv + 1]; o.z = tile[d][vv + 2]; o.w = tile[d][vv + 3];
            *(ushort4*)&Et[(size_t)d * V_ + vs + vv] = o;
        }
    }
}

// Tt[k][b][a*8+c] = T[k][a][b*8+c]   (transpose over (a,b), keep c)
__global__ __launch_bounds__(256) void transT_k(const float* __restrict__ T, float* __restrict__ Tt) {
    for (int q = 0; q < 4; ++q) {
        int id = blockIdx.x * 1024 + q * 256 + threadIdx.x;   // 0..262143
        int k = id >> 17;
        int rem = id & 131071;
        int a = rem >> 10;
        int bc = rem & 1023;
        int b = bc >> 3, c = bc & 7;
        Tt[k * 131072 + b * 1024 + a * 8 + c] = T[id];
    }
}

// ue = select(mm, colmean, x);  qz = softmax_D(ue*keep)*keep  (+ bf16 copy)
__global__ __launch_bounds__(64) void init_k(const float* __restrict__ x, const int* __restrict__ mask,
                                             const int* __restrict__ m_mask, const float* __restrict__ meansum,
                                             float* __restrict__ ue, float* __restrict__ qz,
                                             unsigned short* __restrict__ qzb) {
    int row = blockIdx.x, t = threadIdx.x;
    float keepv = mask[row] ? 1.f : 0.f;
    bool mm = m_mask[row] != 0;
    float pre0 = meansum[t] * (1.f / 32000.f);
    float pre1 = meansum[t + 64] * (1.f / 32000.f);
    float u0 = mm ? pre0 : x[row * 128 + t];
    float u1 = mm ? pre1 : x[row * 128 + t + 64];
    ue[row * 128 + t] = u0;
    ue[row * 128 + t + 64] = u1;
    float sv0 = u0 * keepv, sv1 = u1 * keepv;
    float m = fmaxf(sv0, sv1);
    for (int off = 32; off; off >>= 1) m = fmaxf(m, __shfl_xor(m, off));
    float e0 = __expf(sv0 - m), e1 = __expf(sv1 - m);
    float s = e0 + e1;
    for (int off = 32; off; off >>= 1) s += __shfl_xor(s, off);
    float inv = keepv / s;
    float q0 = e0 * inv, q1 = e1 * inv;
    qz[row * 128 + t] = q0;
    qz[row * 128 + t + 64] = q1;
    qzb[row * 128 + t] = f2bf(q0);
    qzb[row * 128 + t + 64] = f2bf(q1);
}

// ---------- per-iteration kernels ----------

// rowinv[row] = 1 / sum_v exp(qx[row,v])    (|qx| <= ~6, no max-shift needed)
__global__ __launch_bounds__(256) void rowsum_k(const float* __restrict__ qx, float* __restrict__ rowinv) {
    int row = blockIdx.x, t = threadIdx.x;
    const float* p = qx + (size_t)row * V_;
    float s = 0.f;
    for (int v = t; v < V_; v += 256)
        s += __expf(p[v]);
    for (int off = 32; off; off >>= 1) s += __shfl_xor(s, off);
    __shared__ float ss[4];
    int w = t >> 6;
    if ((t & 63) == 0) ss[w] = s;
    __syncthreads();
    if (t == 0)
        rowinv[row] = 1.f / (ss[0] + ss[1] + ss[2] + ss[3]);
}

// exbuf[row][d] (+)= sum_v exp(qx[row,v]) * E[v][d]  — bf16 MFMA split-K
// block = 4 waves; wave w owns rows [bx*64 + w*16, +16) x all 128 d; grid (8,100)
__global__ __launch_bounds__(256) void exgemm_mfma_k(const float* __restrict__ qx,
                                                     const unsigned short* __restrict__ Et,
                                                     float* __restrict__ exbuf) {
    int t = threadIdx.x;
    int w = t >> 6, lane = t & 63;
    int nloc = lane & 15, half = lane >> 4;   // half = quad index 0..3
    int rbase = blockIdx.x * 64 + w * 16;
    int arow = rbase + nloc;
    int k0 = blockIdx.y * 320;
    f32x4 acc[8];
#pragma unroll
    for (int ct = 0; ct < 8; ++ct) acc[ct] = (f32x4){0.f, 0.f, 0.f, 0.f};
    for (int ks = 0; ks < 10; ++ks) {
        int kk = k0 + ks * 32 + half * 8;
        float4 a0 = *(const float4*)&qx[(size_t)arow * V_ + kk];
        float4 a1 = *(const float4*)&qx[(size_t)arow * V_ + kk + 4];
        short8 afr;
        afr[0] = (short)f2bf(__expf(a0.x));
        afr[1] = (short)f2bf(__expf(a0.y));
        afr[2] = (short)f2bf(__expf(a0.z));
        afr[3] = (short)f2bf(__expf(a0.w));
        afr[4] = (short)f2bf(__expf(a1.x));
        afr[5] = (short)f2bf(__expf(a1.y));
        afr[6] = (short)f2bf(__expf(a1.z));
        afr[7] = (short)f2bf(__expf(a1.w));
#pragma unroll
        for (int ct = 0; ct < 8; ++ct) {
            short8 bfr = *(const short8*)&Et[(size_t)(ct * 16 + nloc) * V_ + kk];
            acc[ct] = __builtin_amdgcn_mfma_f32_16x16x32_bf16(afr, bfr, acc[ct], 0, 0, 0);
        }
    }
#pragma unroll
    for (int ct = 0; ct < 8; ++ct) {
        int col = ct * 16 + nloc;
#pragma unroll
        for (int reg = 0; reg < 4; ++reg) {
            int row = rbase + half * 4 + reg;
            atomicAdd(&exbuf[row * 128 + col], acc[ct][reg]);
        }
    }
}

// ue = mm ? exbuf*rowinv : x
__global__ __launch_bounds__(128) void uecomb_k(const float* __restrict__ x, const int* __restrict__ m_mask,
                                                const float* __restrict__ exbuf, const float* __restrict__ rowinv,
                                                float* __restrict__ ue) {
    int row = blockIdx.x, t = threadIdx.x;
    bool mm = m_mask[row] != 0;
    ue[row * 128 + t] = mm ? exbuf[row * 128 + t] * rowinv[row] : x[row * 128 + t];
}

// U2[(z*2+k)][i][(b*8+c)] = sum_a qz[z,i,a] T[k][a][(b,c)]
// W2[(z*2+k)][j][(a*8+c)] = sum_b qz[z,j,b] Tt[k][b][(a,c)]
__global__ __launch_bounds__(256) void uwgemm_k(const float* __restrict__ qz, const float* __restrict__ T,
                                                const float* __restrict__ Tt, float* __restrict__ U2,
                                                float* __restrict__ W2) {
    int t = threadIdx.x;
    int by = blockIdx.y;            // 16: uw(2) x z(4) x k(2)
    int uw = by >> 3, z = (by >> 1) & 3, k = by & 1;
    int bx = blockIdx.x;            // 32: mt(8) x nt(4)
    int m0 = (bx >> 2) * 16, n = (bx & 3) * 256 + t;
    const float* A = qz + z * 16384;
    const float* Bm = (uw ? Tt : T) + k * 131072;
    float* Cm = (uw ? W2 : U2) + (z * 2 + k) * 131072;
    __shared__ float aL[2048];
    for (int idx = t; idx < 2048; idx += 256)
        aL[idx] = A[(m0 + (idx >> 7)) * 128 + (idx & 127)];
    __syncthreads();
    float acc[16];
#pragma unroll
    for (int m = 0; m < 16; ++m) acc[m] = 0.f;
    for (int kq = 0; kq < 32; ++kq) {
        float b0 = Bm[(kq * 4 + 0) * 1024 + n];
        float b1 = Bm[(kq * 4 + 1) * 1024 + n];
        float b2 = Bm[(kq * 4 + 2) * 1024 + n];
        float b3 = Bm[(kq * 4 + 3) * 1024 + n];
#pragma unroll
        for (int m = 0; m < 16; ++m) {
            const float4 aq = *(const float4*)&aL[m * 128 + kq * 4];
            acc[m] += aq.x * b0 + aq.y * b1 + aq.z * b2 + aq.w * b3;
        }
    }
#pragma unroll
    for (int m = 0; m < 16; ++m)
        Cm[(m0 + m) * 1024 + n] = acc[m];
}

// q_hn[z,c,i,:] = softmax_j( F ) with diag/invalid = -NEG;  also writes transposed copy
__global__ __launch_bounds__(256) void qhn_k(const float* __restrict__ qz, const float* __restrict__ U2,
                                             const int* __restrict__ mask, float* __restrict__ qhn,
                                             float* __restrict__ qhnT) {
    int bid = blockIdx.x;
    int z = bid >> 7, i = bid & 127;
    int t = threadIdx.x;
    __shared__ float uL[2048];
    __shared__ float qzC[128 * 33];
    __shared__ float fL[1024];
    {
        const float* ub = U2 + z * 262144 + i * 1024;
        for (int idx = t; idx < 2048; idx += 256) {
            int k = idx >> 10, bc = idx & 1023;
            uL[idx] = ub[k * 131072 + bc];
        }
    }
    int j = t & 127, ch = t >> 7;
    int kSel = (j > i) ? 0 : 1;
    const int ubase = kSel * 1024 + ch;
    float acc4[4] = {0.f, 0.f, 0.f, 0.f};
    for (int bcn = 0; bcn < 4; ++bcn) {
        __syncthreads();
        for (int idx = t; idx < 4096; idx += 256) {
            int jj = idx >> 5, bb = idx & 31;
            qzC[jj * 33 + bb] = qz[z * 16384 + jj * 128 + bcn * 32 + bb];
        }
        __syncthreads();
#pragma unroll 8
        for (int bb = 0; bb < 32; ++bb) {
            float qv = qzC[j * 33 + bb];
            int b8 = (bcn * 32 + bb) * 8;
            acc4[0] += uL[ubase + b8] * qv;
            acc4[1] += uL[ubase + b8 + 2] * qv;
            acc4[2] += uL[ubase + b8 + 4] * qv;
            acc4[3] += uL[ubase + b8 + 6] * qv;
        }
    }
    bool vi = mask[z * 128 + i] != 0;
    bool vj = mask[z * 128 + j] != 0;
#pragma unroll
    for (int g = 0; g < 4; ++g) {
        float F = acc4[g];
        if (j == i) F -= NEGC;
        if (!vi || !vj) F = -NEGC;
        fL[(2 * g + ch) * 128 + j] = F;
    }
    __syncthreads();
    int c = t >> 5, lane = t & 31;
    float mval = -3.4e38f;
#pragma unroll
    for (int q = 0; q < 4; ++q) mval = fmaxf(mval, fL[c * 128 + lane + q * 32]);
    for (int off = 16; off; off >>= 1) mval = fmaxf(mval, __shfl_xor(mval, off, 32));
    float ssum = 0.f;
#pragma unroll
    for (int q = 0; q < 4; ++q) ssum += __expf(fL[c * 128 + lane + q * 32] - mval);
    for (int off = 16; off; off >>= 1) ssum += __shfl_xor(ssum, off, 32);
    float inv = 1.f / ssum;
#pragma unroll
    for (int q = 0; q < 4; ++q) {
        int j2 = lane + q * 32;
        float val = __expf(fL[c * 128 + j2] - mval) * inv;
        qhn[((z * 8 + c) * 128 + i) * 128 + j2] = val;
        qhnT[((z * 8 + c) * 128 + j2) * 128 + i] = val;
    }
}

// mode 0: G1[z,i,a] = sum_{c,s} hn[c,i,s] * W2[k(s,i)][s][(a,c)]   (k=0 iff s>i)
// mode 1: G2[z,j,b] = sum_{c,s} hn[c,s,j] * U2[k(s,j)][s][(b,c)]   (k=0 iff s<j)
__global__ __launch_bounds__(256) void gkern_k(const float* __restrict__ qhn, const float* __restrict__ qhnT,
                                               const float* __restrict__ U2, const float* __restrict__ W2,
                                               float* __restrict__ g1, float* __restrict__ g2) {
    int mode = blockIdx.y;
    int z = blockIdx.x >> 5;
    int t0 = (blockIdx.x & 31) * 4;
    int t = threadIdx.x;
    __shared__ float hnL[4 * 8 * 128];   // [ii][c][s]
    __shared__ float red[2 * 4 * 128];
    const float* hsrc = mode ? qhnT : qhn;
    for (int idx = t; idx < 4096; idx += 256) {
        int ii = idx >> 10, rem = idx & 1023;
        int c = rem >> 7, s = rem & 127;
        hnL[idx] = hsrc[((z * 8 + c) * 128 + t0 + ii) * 128 + s];
    }
    __syncthreads();
    int a = t & 127, ch = t >> 7, cb = ch * 4;
    const float* M0 = (mode ? U2 : W2) + z * 262144;
    const float* M1 = M0 + 131072;
    float acc[4] = {0.f, 0.f, 0.f, 0.f};
    const float4 zero4 = {0.f, 0.f, 0.f, 0.f};
    for (int s = 0; s < 128; ++s) {
        bool n0 = mode ? (s < t0 + 3) : (s > t0);
        bool n1 = mode ? (s > t0) : (s < t0 + 3);
        float4 w0 = n0 ? *(const float4*)&M0[s * 1024 + a * 8 + cb] : zero4;
        float4 w1 = n1 ? *(const float4*)&M1[s * 1024 + a * 8 + cb] : zero4;
#pragma unroll
        for (int ii = 0; ii < 4; ++ii) {
            int o = t0 + ii;
            bool u0 = mode ? (s < o) : (s > o);
            float4 wv = u0 ? w0 : w1;
            const float* hrow = &hnL[(ii * 8 + cb) * 128 + s];
            acc[ii] += hrow[0] * wv.x + hrow[128] * wv.y + hrow[256] * wv.z + hrow[384] * wv.w;
        }
    }
#pragma unroll
    for (int ii = 0; ii < 4; ++ii) red[(ch * 4 + ii) * 128 + a] = acc[ii];
    __syncthreads();
    if (ch == 0) {
        float* Gout = mode ? g2 : g1;
#pragma unroll
        for (int ii = 0; ii < 4; ++ii) {
            float v = red[ii * 128 + t] + red[(4 + ii) * 128 + t];
            Gout[(z * 128 + t0 + ii) * 128 + t] = v;
        }
    }
}

// qz = softmax_D(ue + g1 + g2) * keep   (+ bf16 copy)
__global__ __launch_bounds__(64) void zupd_k(const float* __restrict__ ue, const float* __restrict__ g1,
                                             const float* __restrict__ g2, const int* __restrict__ mask,
                                             float* __restrict__ qz, unsigned short* __restrict__ qzb) {
    int row = blockIdx.x, t = threadIdx.x;
    float keepv = mask[row] ? 1.f : 0.f;
    int b = row * 128;
    float v0 = ue[b + t] + g1[b + t] + g2[b + t];
    float v1 = ue[b + t + 64] + g1[b + t + 64] + g2[b + t + 64];
    float m = fmaxf(v0, v1);
    for (int off = 32; off; off >>= 1) m = fmaxf(m, __shfl_xor(m, off));
    float e0 = __expf(v0 - m), e1 = __expf(v1 - m);
    float s = e0 + e1;
    for (int off = 32; off; off >>= 1) s += __shfl_xor(s, off);
    float inv = keepv / s;
    float q0 = e0 * inv, q1 = e1 * inv;
    qz[b + t] = q0;
    qz[b + t + 64] = q1;
    qzb[b + t] = f2bf(q0);
    qzb[b + t + 64] = f2bf(q1);
}

// out[row][v] = sum_a qz[row][a] * E[v][a]   — bf16 MFMA NT-GEMM
__global__ __launch_bounds__(256) void msgx_mfma_k(const unsigned short* __restrict__ qzb,
                                                   const unsigned short* __restrict__ Eb,
                                                   float* __restrict__ out) {
    int t = threadIdx.x;
    int w = t >> 6, lane = t & 63;
    int nloc = lane & 15, half = lane >> 4;
    int rt0 = blockIdx.x * 64;
    int cb0 = blockIdx.y * 256 + w * 64;
    short8 afr[4][4];   // [rowtile][kstep]
#pragma unroll
    for (int r = 0; r < 4; ++r)
#pragma unroll
        for (int s = 0; s < 4; ++s)
            afr[r][s] = *(const short8*)&qzb[(rt0 + r * 16 + nloc) * 128 + s * 32 + half * 8];
    f32x4 acc[4][4];    // [rowtile][coltile]
#pragma unroll
    for (int r = 0; r < 4; ++r)
#pragma unroll
        for (int ct = 0; ct < 4; ++ct)
            acc[r][ct] = (f32x4){0.f, 0.f, 0.f, 0.f};
#pragma unroll
    for (int ct = 0; ct < 4; ++ct) {
#pragma unroll
        for (int s = 0; s < 4; ++s) {
            short8 bfr = *(const short8*)&Eb[(size_t)(cb0 + ct * 16 + nloc) * 128 + s * 32 + half * 8];
#pragma unroll
            for (int r = 0; r < 4; ++r)
                acc[r][ct] = __builtin_amdgcn_mfma_f32_16x16x32_bf16(afr[r][s], bfr, acc[r][ct], 0, 0, 0);
        }
    }
#pragma unroll
    for (int r = 0; r < 4; ++r)
#pragma unroll
        for (int ct = 0; ct < 4; ++ct) {
            int col = cb0 + ct * 16 + nloc;
#pragma unroll
            for (int reg = 0; reg < 4; ++reg) {
                int row = rt0 + r * 16 + half * 4 + reg;
                out[(size_t)row * V_ + col] = acc[r][ct][reg];
            }
        }
}

extern "C" void kernel_launch(void* const* d_in, const int* in_sizes, int n_in,
                              void* d_out, int out_size, void* d_ws, size_t ws_size,
                              hipStream_t stream) {
    const float* x     = (const float*)d_in[0];   // [B,L,D]
    const int*   mask  = (const int*)d_in[1];     // [B,L]
    const float* E     = (const float*)d_in[2];   // [V,D]
    const int*   mmask = (const int*)d_in[3];     // [B,L]
    const float* T     = (const float*)d_in[4];   // [2,D,D,H]
    float* out = (float*)d_out;                   // [B,L,V]

    float* w = (float*)d_ws;
    float* meansum = w;                 // 128
    float* ue      = w + 128;           // 65536
    float* qz      = ue + 65536;        // 65536
    float* exbuf   = qz + 65536;        // 65536
    float* g1      = exbuf + 65536;     // 65536
    float* g2      = g1 + 65536;        // 65536
    float* rowinv  = g2 + 65536;        // 1024
    float* Tt      = rowinv + 1024;     // 262144
    float* U2      = Tt + 262144;       // 1048576
    float* W2      = U2 + 1048576;      // 1048576
    float* qhn     = W2 + 1048576;      // 524288
    float* qhnT    = qhn + 524288;      // 524288
    unsigned short* qzb = (unsigned short*)(qhnT + 524288);            // 65536 ushort
    unsigned short* Eb  = (unsigned short*)(qhnT + 524288 + 32768);    // 4,096,000 ushort
    unsigned short* Et  = Eb + 4096000;                                // 4,096,000 ushort  (~31.5 MB total)

    hipMemsetAsync(meansum, 0, 128 * sizeof(float), stream);
    colsum_k<<<125, 256, 0, stream>>>(E, meansum);
    cvtE_k<<<4000, 256, 0, stream>>>(E, Eb);
    transEt_k<<<125, 256, 0, stream>>>(E, Et);
    transT_k<<<256, 256, 0, stream>>>(T, Tt);
    init_k<<<512, 64, 0, stream>>>(x, mask, mmask, meansum, ue, qz, qzb);

    for (int it = 0; it < 4; ++it) {
        if (it) {
            rowsum_k<<<512, 256, 0, stream>>>(out, rowinv);
            hipMemsetAsync(exbuf, 0, 65536 * sizeof(float), stream);
            exgemm_mfma_k<<<dim3(8, 100), 256, 0, stream>>>(out, Et, exbuf);
            uecomb_k<<<512, 128, 0, stream>>>(x, mmask, exbuf, rowinv, ue);
        }
        uwgemm_k<<<dim3(32, 16), 256, 0, stream>>>(qz, T, Tt, U2, W2);
        qhn_k<<<512, 256, 0, stream>>>(qz, U2, mask, qhn, qhnT);
        gkern_k<<<dim3(128, 2), 256, 0, stream>>>(qhn, qhnT, U2, W2, g1, g2);
        zupd_k<<<512, 64, 0, stream>>>(ue, g1, g2, mask, qz, qzb);
        msgx_mfma_k<<<dim3(8, 125), 256, 0, stream>>>(qzb, Eb, out);
    }
}

// Round 5
// 727.037 us; speedup vs baseline: 3.0971x; 1.4303x over previous
//
#include <hip/hip_runtime.h>
#include <math.h>

#define L_ 128
#define D_ 128
#define H_ 8
#define V_ 32000
#define NEGC 1e9f

typedef short short8 __attribute__((ext_vector_type(8)));
typedef float f32x4 __attribute__((ext_vector_type(4)));
typedef unsigned short ushort8v __attribute__((ext_vector_type(8)));

__device__ __forceinline__ unsigned short f2bf(float x) {
    unsigned int u = __float_as_uint(x);
    unsigned int r = (u + 0x7fff + ((u >> 16) & 1)) >> 16;
    return (unsigned short)r;
}

// ---------- one-time precompute ----------

// meansum[d] = sum_v E[v][d]
__global__ __launch_bounds__(256) void colsum_k(const float* __restrict__ E, float* __restrict__ meansum) {
    int t = threadIdx.x;
    int d = t & 127, h = t >> 7;
    int v0 = blockIdx.x * 256;
    float s = 0.f;
    for (int p = 0; p < 128; ++p)
        s += E[(v0 + h + 2 * p) * 128 + d];
    __shared__ float red[256];
    red[t] = s;
    __syncthreads();
    if (h == 0) atomicAdd(&meansum[d], red[d] + red[128 + d]);
}

// E (fp32, [V,128]) -> Eb (bf16, row-major)
__global__ __launch_bounds__(256) void cvtE_k(const float* __restrict__ E, unsigned short* __restrict__ Eb) {
    int i = blockIdx.x * 256 + threadIdx.x;   // x4 floats
    float4 v = ((const float4*)E)[i];
    ushort4 o;
    o.x = f2bf(v.x); o.y = f2bf(v.y); o.z = f2bf(v.z); o.w = f2bf(v.w);
    ((ushort4*)Eb)[i] = o;
}

// Et[d][v] = bf16(E[v][d])  — LDS-tiled transpose, 256 v x 128 d per block
__global__ __launch_bounds__(256) void transEt_k(const float* __restrict__ E, unsigned short* __restrict__ Et) {
    __shared__ unsigned short tile[128][68];
    int t = threadIdx.x;
    int v0 = blockIdx.x * 256;
    for (int sub = 0; sub < 4; ++sub) {
        int vs = v0 + sub * 64;
        __syncthreads();
#pragma unroll
        for (int i = 0; i < 8; ++i) {
            int idx = i * 256 + t;          // 2048 float4 = 64 v x 128 d
            int v = idx >> 5;
            int d4 = (idx & 31) * 4;
            float4 val = *(const float4*)&E[(size_t)(vs + v) * 128 + d4];
            tile[d4 + 0][v] = f2bf(val.x);
            tile[d4 + 1][v] = f2bf(val.y);
            tile[d4 + 2][v] = f2bf(val.z);
            tile[d4 + 3][v] = f2bf(val.w);
        }
        __syncthreads();
#pragma unroll
        for (int i = 0; i < 8; ++i) {
            int idx = i * 256 + t;          // 2048 ushort4 = 128 d x 64 v
            int d = idx >> 4;
            int vv = (idx & 15) * 4;
            ushort4 o;
            o.x = tile[d][vv]; o.y = tile[d][vv + 1]; o.z = tile[d][vv + 2]; o.w = tile[d][vv + 3];
            *(ushort4*)&Et[(size_t)d * V_ + vs + vv] = o;
        }
    }
}

// Tt[k][b][a*8+c] = T[k][a][b*8+c]   (transpose over (a,b), keep c)
__global__ __launch_bounds__(256) void transT_k(const float* __restrict__ T, float* __restrict__ Tt) {
    for (int q = 0; q < 4; ++q) {
        int id = blockIdx.x * 1024 + q * 256 + threadIdx.x;   // 0..262143
        int k = id >> 17;
        int rem = id & 131071;
        int a = rem >> 10;
        int bc = rem & 1023;
        int b = bc >> 3, c = bc & 7;
        Tt[k * 131072 + b * 1024 + a * 8 + c] = T[id];
    }
}

// ue = select(mm, colmean, x);  qz = softmax_D(ue*keep)*keep  (+ bf16 copy)
__global__ __launch_bounds__(64) void init_k(const float* __restrict__ x, const int* __restrict__ mask,
                                             const int* __restrict__ m_mask, const float* __restrict__ meansum,
                                             float* __restrict__ ue, float* __restrict__ qz,
                                             unsigned short* __restrict__ qzb) {
    int row = blockIdx.x, t = threadIdx.x;
    float keepv = mask[row] ? 1.f : 0.f;
    bool mm = m_mask[row] != 0;
    float pre0 = meansum[t] * (1.f / 32000.f);
    float pre1 = meansum[t + 64] * (1.f / 32000.f);
    float u0 = mm ? pre0 : x[row * 128 + t];
    float u1 = mm ? pre1 : x[row * 128 + t + 64];
    ue[row * 128 + t] = u0;
    ue[row * 128 + t + 64] = u1;
    float sv0 = u0 * keepv, sv1 = u1 * keepv;
    float m = fmaxf(sv0, sv1);
    for (int off = 32; off; off >>= 1) m = fmaxf(m, __shfl_xor(m, off));
    float e0 = __expf(sv0 - m), e1 = __expf(sv1 - m);
    float s = e0 + e1;
    for (int off = 32; off; off >>= 1) s += __shfl_xor(s, off);
    float inv = keepv / s;
    float q0 = e0 * inv, q1 = e1 * inv;
    qz[row * 128 + t] = q0;
    qz[row * 128 + t + 64] = q1;
    qzb[row * 128 + t] = f2bf(q0);
    qzb[row * 128 + t + 64] = f2bf(q1);
}

// ---------- per-iteration kernels ----------

// rowinv[row] = 1 / sum_v exp(qx[row,v])    (|qx| <= ~6, no max-shift needed)
__global__ __launch_bounds__(256) void rowsum_k(const float* __restrict__ qx, float* __restrict__ rowinv) {
    int row = blockIdx.x, t = threadIdx.x;
    const float* p = qx + (size_t)row * V_;
    float s = 0.f;
    for (int v = t; v < V_; v += 256)
        s += __expf(p[v]);
    for (int off = 32; off; off >>= 1) s += __shfl_xor(s, off);
    __shared__ float ss[4];
    int w = t >> 6;
    if ((t & 63) == 0) ss[w] = s;
    __syncthreads();
    if (t == 0)
        rowinv[row] = 1.f / (ss[0] + ss[1] + ss[2] + ss[3]);
}

// exbuf[row][d] (+)= sum_v exp(qx[row,v]) * E[v][d]  — bf16 MFMA split-K
__global__ __launch_bounds__(256) void exgemm_mfma_k(const float* __restrict__ qx,
                                                     const unsigned short* __restrict__ Et,
                                                     float* __restrict__ exbuf) {
    int t = threadIdx.x;
    int w = t >> 6, lane = t & 63;
    int nloc = lane & 15, half = lane >> 4;   // half = quad index 0..3
    int rbase = blockIdx.x * 64 + w * 16;
    int arow = rbase + nloc;
    int k0 = blockIdx.y * 320;
    f32x4 acc[8];
#pragma unroll
    for (int ct = 0; ct < 8; ++ct) acc[ct] = (f32x4){0.f, 0.f, 0.f, 0.f};
    for (int ks = 0; ks < 10; ++ks) {
        int kk = k0 + ks * 32 + half * 8;
        float4 a0 = *(const float4*)&qx[(size_t)arow * V_ + kk];
        float4 a1 = *(const float4*)&qx[(size_t)arow * V_ + kk + 4];
        short8 afr;
        afr[0] = (short)f2bf(__expf(a0.x));
        afr[1] = (short)f2bf(__expf(a0.y));
        afr[2] = (short)f2bf(__expf(a0.z));
        afr[3] = (short)f2bf(__expf(a0.w));
        afr[4] = (short)f2bf(__expf(a1.x));
        afr[5] = (short)f2bf(__expf(a1.y));
        afr[6] = (short)f2bf(__expf(a1.z));
        afr[7] = (short)f2bf(__expf(a1.w));
#pragma unroll
        for (int ct = 0; ct < 8; ++ct) {
            short8 bfr = *(const short8*)&Et[(size_t)(ct * 16 + nloc) * V_ + kk];
            acc[ct] = __builtin_amdgcn_mfma_f32_16x16x32_bf16(afr, bfr, acc[ct], 0, 0, 0);
        }
    }
#pragma unroll
    for (int ct = 0; ct < 8; ++ct) {
        int col = ct * 16 + nloc;
#pragma unroll
        for (int reg = 0; reg < 4; ++reg) {
            int row = rbase + half * 4 + reg;
            atomicAdd(&exbuf[row * 128 + col], acc[ct][reg]);
        }
    }
}

// ue = mm ? exbuf*rowinv : x
__global__ __launch_bounds__(128) void uecomb_k(const float* __restrict__ x, const int* __restrict__ m_mask,
                                                const float* __restrict__ exbuf, const float* __restrict__ rowinv,
                                                float* __restrict__ ue) {
    int row = blockIdx.x, t = threadIdx.x;
    bool mm = m_mask[row] != 0;
    ue[row * 128 + t] = mm ? exbuf[row * 128 + t] * rowinv[row] : x[row * 128 + t];
}

// U2[(z*2+k)][i][(b*8+c)] = sum_a qz[z,i,a] T[k][a][(b,c)]   (fp32, for qhn_k)
//   + bf16 kc-contiguous transposes for gkern MFMA:
// uw=0: Ut[(z*2+k)][b][c*128+i] = bf16(U2 value)
// uw=1: Wt[(z*2+k)][a][c*128+j] = bf16(W2 value)   (fp32 W2 no longer stored)
__global__ __launch_bounds__(256) void uwgemm_k(const float* __restrict__ qz, const float* __restrict__ T,
                                                const float* __restrict__ Tt, float* __restrict__ U2,
                                                unsigned short* __restrict__ Ut, unsigned short* __restrict__ Wt) {
    int t = threadIdx.x;
    int by = blockIdx.y;            // 16: uw(2) x z(4) x k(2)
    int uw = by >> 3, z = (by >> 1) & 3, k = by & 1;
    int bx = blockIdx.x;            // 32: mt(8) x nt(4)
    int m0 = (bx >> 2) * 16, n = (bx & 3) * 256 + t;
    const float* A = qz + z * 16384;
    const float* Bm = (uw ? Tt : T) + k * 131072;
    __shared__ float aL[2048];
    for (int idx = t; idx < 2048; idx += 256)
        aL[idx] = A[(m0 + (idx >> 7)) * 128 + (idx & 127)];
    __syncthreads();
    float acc[16];
#pragma unroll
    for (int m = 0; m < 16; ++m) acc[m] = 0.f;
    for (int kq = 0; kq < 32; ++kq) {
        float b0 = Bm[(kq * 4 + 0) * 1024 + n];
        float b1 = Bm[(kq * 4 + 1) * 1024 + n];
        float b2 = Bm[(kq * 4 + 2) * 1024 + n];
        float b3 = Bm[(kq * 4 + 3) * 1024 + n];
#pragma unroll
        for (int m = 0; m < 16; ++m) {
            const float4 aq = *(const float4*)&aL[m * 128 + kq * 4];
            acc[m] += aq.x * b0 + aq.y * b1 + aq.z * b2 + aq.w * b3;
        }
    }
    if (uw == 0) {
        float* Cm = U2 + (z * 2 + k) * 131072;
#pragma unroll
        for (int m = 0; m < 16; ++m)
            Cm[(m0 + m) * 1024 + n] = acc[m];
    }
    // bf16 transposed write: [bc-row][c*128 + outrow]
    int bb = n >> 3, cc = n & 7;
    ushort8v p0, p1;
#pragma unroll
    for (int m = 0; m < 8; ++m) { p0[m] = f2bf(acc[m]); p1[m] = f2bf(acc[8 + m]); }
    unsigned short* To = (uw ? Wt : Ut) + ((size_t)(z * 2 + k) * 128 + bb) * 1024 + cc * 128 + m0;
    *(ushort8v*)&To[0] = p0;
    *(ushort8v*)&To[8] = p1;
}

// q_hn = softmax_j(F) with diag/invalid = -NEG.  Emits 4 masked bf16 copies for gkern MFMA:
//  A0b[z,c,i,s] = hn*(s>i), A1b = hn*(s<i); A0Tb[z,c,j,s] = hnT*(s<j), A1Tb = hnT*(s>j)
__global__ __launch_bounds__(256) void qhn_k(const float* __restrict__ qz, const float* __restrict__ U2,
                                             const int* __restrict__ mask,
                                             unsigned short* __restrict__ A0b, unsigned short* __restrict__ A1b,
                                             unsigned short* __restrict__ A0Tb, unsigned short* __restrict__ A1Tb) {
    int bid = blockIdx.x;
    int z = bid >> 7, i = bid & 127;
    int t = threadIdx.x;
    __shared__ float uL[2048];
    __shared__ float qzC[128 * 33];
    __shared__ float fL[1024];
    {
        const float* ub = U2 + z * 262144 + i * 1024;
        for (int idx = t; idx < 2048; idx += 256) {
            int k = idx >> 10, bc = idx & 1023;
            uL[idx] = ub[k * 131072 + bc];
        }
    }
    int j = t & 127, ch = t >> 7;
    int kSel = (j > i) ? 0 : 1;
    const int ubase = kSel * 1024 + ch;
    float acc4[4] = {0.f, 0.f, 0.f, 0.f};
    for (int bcn = 0; bcn < 4; ++bcn) {
        __syncthreads();
        for (int idx = t; idx < 4096; idx += 256) {
            int jj = idx >> 5, bb = idx & 31;
            qzC[jj * 33 + bb] = qz[z * 16384 + jj * 128 + bcn * 32 + bb];
        }
        __syncthreads();
#pragma unroll 8
        for (int bb = 0; bb < 32; ++bb) {
            float qv = qzC[j * 33 + bb];
            int b8 = (bcn * 32 + bb) * 8;
            acc4[0] += uL[ubase + b8] * qv;
            acc4[1] += uL[ubase + b8 + 2] * qv;
            acc4[2] += uL[ubase + b8 + 4] * qv;
            acc4[3] += uL[ubase + b8 + 6] * qv;
        }
    }
    bool vi = mask[z * 128 + i] != 0;
    bool vj = mask[z * 128 + j] != 0;
#pragma unroll
    for (int g = 0; g < 4; ++g) {
        float F = acc4[g];
        if (j == i) F -= NEGC;
        if (!vi || !vj) F = -NEGC;
        fL[(2 * g + ch) * 128 + j] = F;
    }
    __syncthreads();
    int c = t >> 5, lane = t & 31;
    float mval = -3.4e38f;
#pragma unroll
    for (int q = 0; q < 4; ++q) mval = fmaxf(mval, fL[c * 128 + lane + q * 32]);
    for (int off = 16; off; off >>= 1) mval = fmaxf(mval, __shfl_xor(mval, off, 32));
    float ssum = 0.f;
#pragma unroll
    for (int q = 0; q < 4; ++q) ssum += __expf(fL[c * 128 + lane + q * 32] - mval);
    for (int off = 16; off; off >>= 1) ssum += __shfl_xor(ssum, off, 32);
    float inv = 1.f / ssum;
    size_t base = (size_t)(z * 8 + c) * 16384;
#pragma unroll
    for (int q = 0; q < 4; ++q) {
        int j2 = lane + q * 32;
        float val = __expf(fL[c * 128 + j2] - mval) * inv;
        unsigned short bv = f2bf(val);
        A0b[base + i * 128 + j2]  = (j2 > i) ? bv : (unsigned short)0;
        A1b[base + i * 128 + j2]  = (j2 < i) ? bv : (unsigned short)0;
        A0Tb[base + j2 * 128 + i] = (i < j2) ? bv : (unsigned short)0;
        A1Tb[base + j2 * 128 + i] = (i > j2) ? bv : (unsigned short)0;
    }
}

// gkern as NT bf16 MFMA:  mode0: G1[z,i,a] = sum_kc A0b[i,kc]*Wt0[a,kc] + A1b[i,kc]*Wt1[a,kc]
//                         mode1: G2[z,j,b] = sum_kc A0Tb[j,kc]*Ut0[b,kc] + A1Tb[j,kc]*Ut1[b,kc]
// kc = c*128+s (K=1024). One wave per block; grid (256, 2): bx = z(4) x itile(8) x atile(8).
__global__ __launch_bounds__(64) void gkern_mfma_k(const unsigned short* __restrict__ A0b,
                                                   const unsigned short* __restrict__ A1b,
                                                   const unsigned short* __restrict__ A0Tb,
                                                   const unsigned short* __restrict__ A1Tb,
                                                   const unsigned short* __restrict__ Ut,
                                                   const unsigned short* __restrict__ Wt,
                                                   float* __restrict__ g1, float* __restrict__ g2) {
    int mode = blockIdx.y;
    int bx = blockIdx.x;
    int z = bx >> 6, it = (bx >> 3) & 7, at = bx & 7;
    int lane = threadIdx.x;
    int nloc = lane & 15, half = lane >> 4;
    int i0 = it * 16, a0 = at * 16;
    const unsigned short* Am0 = (mode ? A0Tb : A0b) + (size_t)z * 131072;
    const unsigned short* Am1 = (mode ? A1Tb : A1b) + (size_t)z * 131072;
    const unsigned short* Bt = mode ? Ut : Wt;
    const unsigned short* B0 = Bt + (size_t)(z * 2 + 0) * 131072 + (size_t)(a0 + nloc) * 1024;
    const unsigned short* B1 = Bt + (size_t)(z * 2 + 1) * 131072 + (size_t)(a0 + nloc) * 1024;
    const unsigned short* Ar0 = Am0 + (size_t)(i0 + nloc) * 128;
    const unsigned short* Ar1 = Am1 + (size_t)(i0 + nloc) * 128;
    f32x4 acc = (f32x4){0.f, 0.f, 0.f, 0.f};
#pragma unroll
    for (int c = 0; c < 8; ++c) {
#pragma unroll
        for (int sb = 0; sb < 4; ++sb) {
            int s0 = sb * 32 + half * 8;
            short8 av0 = *(const short8*)&Ar0[c * 16384 + s0];
            short8 bv0 = *(const short8*)&B0[c * 128 + s0];
            acc = __builtin_amdgcn_mfma_f32_16x16x32_bf16(av0, bv0, acc, 0, 0, 0);
            short8 av1 = *(const short8*)&Ar1[c * 16384 + s0];
            short8 bv1 = *(const short8*)&B1[c * 128 + s0];
            acc = __builtin_amdgcn_mfma_f32_16x16x32_bf16(av1, bv1, acc, 0, 0, 0);
        }
    }
    float* G = mode ? g2 : g1;
#pragma unroll
    for (int reg = 0; reg < 4; ++reg)
        G[(z * 128 + i0 + half * 4 + reg) * 128 + a0 + nloc] = acc[reg];
}

// qz = softmax_D(ue + g1 + g2) * keep   (+ bf16 copy)
__global__ __launch_bounds__(64) void zupd_k(const float* __restrict__ ue, const float* __restrict__ g1,
                                             const float* __restrict__ g2, const int* __restrict__ mask,
                                             float* __restrict__ qz, unsigned short* __restrict__ qzb) {
    int row = blockIdx.x, t = threadIdx.x;
    float keepv = mask[row] ? 1.f : 0.f;
    int b = row * 128;
    float v0 = ue[b + t] + g1[b + t] + g2[b + t];
    float v1 = ue[b + t + 64] + g1[b + t + 64] + g2[b + t + 64];
    float m = fmaxf(v0, v1);
    for (int off = 32; off; off >>= 1) m = fmaxf(m, __shfl_xor(m, off));
    float e0 = __expf(v0 - m), e1 = __expf(v1 - m);
    float s = e0 + e1;
    for (int off = 32; off; off >>= 1) s += __shfl_xor(s, off);
    float inv = keepv / s;
    float q0 = e0 * inv, q1 = e1 * inv;
    qz[b + t] = q0;
    qz[b + t + 64] = q1;
    qzb[b + t] = f2bf(q0);
    qzb[b + t + 64] = f2bf(q1);
}

// out[row][v] = sum_a qz[row][a] * E[v][a]   — bf16 MFMA NT-GEMM
__global__ __launch_bounds__(256) void msgx_mfma_k(const unsigned short* __restrict__ qzb,
                                                   const unsigned short* __restrict__ Eb,
                                                   float* __restrict__ out) {
    int t = threadIdx.x;
    int w = t >> 6, lane = t & 63;
    int nloc = lane & 15, half = lane >> 4;
    int rt0 = blockIdx.x * 64;
    int cb0 = blockIdx.y * 256 + w * 64;
    short8 afr[4][4];   // [rowtile][kstep]
#pragma unroll
    for (int r = 0; r < 4; ++r)
#pragma unroll
        for (int s = 0; s < 4; ++s)
            afr[r][s] = *(const short8*)&qzb[(rt0 + r * 16 + nloc) * 128 + s * 32 + half * 8];
    f32x4 acc[4][4];    // [rowtile][coltile]
#pragma unroll
    for (int r = 0; r < 4; ++r)
#pragma unroll
        for (int ct = 0; ct < 4; ++ct)
            acc[r][ct] = (f32x4){0.f, 0.f, 0.f, 0.f};
#pragma unroll
    for (int ct = 0; ct < 4; ++ct) {
#pragma unroll
        for (int s = 0; s < 4; ++s) {
            short8 bfr = *(const short8*)&Eb[(size_t)(cb0 + ct * 16 + nloc) * 128 + s * 32 + half * 8];
#pragma unroll
            for (int r = 0; r < 4; ++r)
                acc[r][ct] = __builtin_amdgcn_mfma_f32_16x16x32_bf16(afr[r][s], bfr, acc[r][ct], 0, 0, 0);
        }
    }
#pragma unroll
    for (int r = 0; r < 4; ++r)
#pragma unroll
        for (int ct = 0; ct < 4; ++ct) {
            int col = cb0 + ct * 16 + nloc;
#pragma unroll
            for (int reg = 0; reg < 4; ++reg) {
                int row = rt0 + r * 16 + half * 4 + reg;
                out[(size_t)row * V_ + col] = acc[r][ct][reg];
            }
        }
}

extern "C" void kernel_launch(void* const* d_in, const int* in_sizes, int n_in,
                              void* d_out, int out_size, void* d_ws, size_t ws_size,
                              hipStream_t stream) {
    const float* x     = (const float*)d_in[0];   // [B,L,D]
    const int*   mask  = (const int*)d_in[1];     // [B,L]
    const float* E     = (const float*)d_in[2];   // [V,D]
    const int*   mmask = (const int*)d_in[3];     // [B,L]
    const float* T     = (const float*)d_in[4];   // [2,D,D,H]
    float* out = (float*)d_out;                   // [B,L,V]

    float* w = (float*)d_ws;
    float* meansum = w;                 // 128
    float* ue      = w + 128;           // 65536
    float* qz      = ue + 65536;        // 65536
    float* exbuf   = qz + 65536;        // 65536
    float* g1      = exbuf + 65536;     // 65536
    float* g2      = g1 + 65536;        // 65536
    float* rowinv  = g2 + 65536;        // 1024
    float* Tt      = rowinv + 1024;     // 262144
    float* U2      = Tt + 262144;       // 1048576 (fp32, qhn_k input)
    unsigned short* qzb  = (unsigned short*)(U2 + 1048576);  // 65536
    unsigned short* Eb   = qzb + 65536;                      // 4,096,000
    unsigned short* Et   = Eb + 4096000;                     // 4,096,000
    unsigned short* A0b  = Et + 4096000;                     // 524288
    unsigned short* A1b  = A0b + 524288;                     // 524288
    unsigned short* A0Tb = A1b + 524288;                     // 524288
    unsigned short* A1Tb = A0Tb + 524288;                    // 524288
    unsigned short* Ut   = A1Tb + 524288;                    // 1048576
    unsigned short* Wt   = Ut + 1048576;                     // 1048576   (~30 MiB total)

    hipMemsetAsync(meansum, 0, 128 * sizeof(float), stream);
    colsum_k<<<125, 256, 0, stream>>>(E, meansum);
    cvtE_k<<<4000, 256, 0, stream>>>(E, Eb);
    transEt_k<<<125, 256, 0, stream>>>(E, Et);
    transT_k<<<256, 256, 0, stream>>>(T, Tt);
    init_k<<<512, 64, 0, stream>>>(x, mask, mmask, meansum, ue, qz, qzb);

    for (int it = 0; it < 4; ++it) {
        if (it) {
            rowsum_k<<<512, 256, 0, stream>>>(out, rowinv);
            hipMemsetAsync(exbuf, 0, 65536 * sizeof(float), stream);
            exgemm_mfma_k<<<dim3(8, 100), 256, 0, stream>>>(out, Et, exbuf);
            uecomb_k<<<512, 128, 0, stream>>>(x, mmask, exbuf, rowinv, ue);
        }
        uwgemm_k<<<dim3(32, 16), 256, 0, stream>>>(qz, T, Tt, U2, Ut, Wt);
        qhn_k<<<512, 256, 0, stream>>>(qz, U2, mask, A0b, A1b, A0Tb, A1Tb);
        gkern_mfma_k<<<dim3(256, 2), 64, 0, stream>>>(A0b, A1b, A0Tb, A1Tb, Ut, Wt, g1, g2);
        zupd_k<<<512, 64, 0, stream>>>(ue, g1, g2, mask, qz, qzb);
        msgx_mfma_k<<<dim3(8, 125), 256, 0, stream>>>(qzb, Eb, out);
    }
}